// Round 6
// baseline (1907.319 us; speedup 1.0000x reference)
//
#include <hip/hip_runtime.h>
#include <hip/hip_bf16.h>

// FacePartGAT: dense-graph GATConv x2 + mean + fc on MI355X. ALL I/O fp32.
// e[i,j] = leaky_relu(t_i + s_j) => softmax aggregation factorizes after
// sorting sources by s_j. Exact.
// Round 17: eliminate the per-rank prefix/suffix tables (21.6 MB write +
// ~43 MB read). Queries are bucketed by split-chunk (fused into passB as a
// 3rd block column); passD stages each chunk's 32 e*h rows in LDS once and
// answers its ~32 queries directly with the SAME accumulation order as the
// old table scan + carry addition (absmax unchanged). passAC -> passA
// (partials only). Dispatch count unchanged (13).

#define NNODE 4096
#define CDIM 128
#define TW 132           // partial-table width: 128 features + z at col 128
#define NEG 0.2f
#define CHUNK 32
#define NCHUNK 128       // NNODE / CHUNK

typedef __bf16 bf16x8 __attribute__((ext_vector_type(8)));
typedef float f32x4 __attribute__((ext_vector_type(4)));

__device__ __forceinline__ unsigned short f2b(float f) {
  unsigned int u = __float_as_uint(f);
  u += 0x7fffu + ((u >> 16) & 1u);  // RTNE
  return (unsigned short)(u >> 16);
}

// One kernel: [0,3072) convert x -> bf16; [3072,3168) W1 transpose;
// [3168,3184) W2 transpose; [3184,3216) zero s1/t1; [3216,3224) zero s2/t2.
__global__ __launch_bounds__(256) void prep_kernel(const float* __restrict__ x,
                                                   const float* __restrict__ W1,
                                                   const float* __restrict__ W2,
                                                   unsigned short* __restrict__ xb,
                                                   unsigned short* __restrict__ W1t,
                                                   unsigned short* __restrict__ W2t,
                                                   float* __restrict__ zs1,
                                                   float* __restrict__ zs2) {
  __shared__ float tile[64][65];
  int b = blockIdx.x, t = threadIdx.x;
  if (b < 3072) {  // convert x: 4096*768/4 quads
    int i = b * 256 + t;
    float4 v = ((const float4*)x)[i];
    ushort4 o;
    o.x = f2b(v.x); o.y = f2b(v.y); o.z = f2b(v.z); o.w = f2b(v.w);
    ((ushort4*)xb)[i] = o;
    return;
  }
  if (b >= 3184) {  // zero s/t accumulators
    float4 z = {0.f, 0.f, 0.f, 0.f};
    if (b < 3216) {
      ((float4*)zs1)[(b - 3184) * 256 + t] = z;       // s1+t1: 32768 floats
    } else {
      ((float4*)zs2)[(b - 3216) * 256 + t] = z;       // s2+t2: 8192 floats
    }
    return;
  }
  const float* W; unsigned short* Wt; int K, N, n0, k0;
  if (b < 3072 + 96) {  // W1 [768,512] -> W1t [512,768]
    int b2 = b - 3072; W = W1; Wt = W1t; K = 768; N = 512;
    n0 = (b2 & 7) * 64; k0 = (b2 >> 3) * 64;
  } else {              // W2 [512,128] -> W2t [128,512]
    int b3 = b - 3072 - 96; W = W2; Wt = W2t; K = 512; N = 128;
    n0 = (b3 & 1) * 64; k0 = (b3 >> 1) * 64;
  }
  for (int p = 0; p < 16; p++) {
    int e = p * 256 + t;
    int rr = e >> 6, cc = e & 63;
    tile[rr][cc] = W[(size_t)(k0 + rr) * N + n0 + cc];
  }
  __syncthreads();
  for (int p = 0; p < 16; p++) {
    int e = p * 256 + t;
    int rr = e >> 6, cc = e & 63;  // rr: n-dir, cc: k-dir
    Wt[(size_t)(n0 + rr) * K + k0 + cc] = f2b(tile[cc][rr]);
  }
}

// C[M,N] = A[M,K] x Bt[N,K]^T, both bf16 K-contig. BK=32, 256 thr = 4 waves
// (2x2). Register prefetch of tile k+1 between LDS barrier and MFMA.
// Fused epilogue: s[h][n] / t[h][n] partial dot products from acc registers.
template <int BM, int BN>
__global__ __launch_bounds__(256) void mfma_gemm_bt(const unsigned short* __restrict__ A,
                                                    const unsigned short* __restrict__ Bt,
                                                    float* __restrict__ C,
                                                    int M, int N, int K,
                                                    float* __restrict__ sAcc,
                                                    float* __restrict__ tAcc,
                                                    const float* __restrict__ av_s,
                                                    const float* __restrict__ av_d) {
  __shared__ __align__(16) unsigned short As[BM * 40];
  __shared__ __align__(16) unsigned short Bs[BN * 40];
  constexpr int WM = BM / 2, WN = BN / 2;
  constexpr int FI = WM / 16, FJ = WN / 16;
  constexpr int EA = BM * 32 / 8;
  constexpr int EB = BN * 32 / 8;
  constexpr int NA = (EA + 255) / 256;
  constexpr int NB = (EB + 255) / 256;
  int tid = threadIdx.x;
  int lane = tid & 63, wave = tid >> 6;
  int wm = (wave >> 1) * WM, wn = (wave & 1) * WN;
  int m0 = blockIdx.y * BM, n0 = blockIdx.x * BN;
  int fm = lane & 15, fq = lane >> 4;
  f32x4 acc[FI][FJ] = {};
  uint4 ar[NA], br[NB];
  // preload tile 0
#pragma unroll
  for (int q = 0; q < NA; q++) {
    int e = q * 256 + tid;
    if (e < EA) {
      int r = e >> 2, kk = (e & 3) * 8;
      ar[q] = *(const uint4*)(A + (size_t)(m0 + r) * K + kk);
    }
  }
#pragma unroll
  for (int q = 0; q < NB; q++) {
    int e = q * 256 + tid;
    if (e < EB) {
      int r = e >> 2, kk = (e & 3) * 8;
      br[q] = *(const uint4*)(Bt + (size_t)(n0 + r) * K + kk);
    }
  }
  for (int k0 = 0; k0 < K; k0 += 32) {
    __syncthreads();  // previous iter's ds_reads done before overwrite
#pragma unroll
    for (int q = 0; q < NA; q++) {
      int e = q * 256 + tid;
      if (e < EA) {
        int r = e >> 2, kk = (e & 3) * 8;
        *(uint4*)&As[r * 40 + kk] = ar[q];
      }
    }
#pragma unroll
    for (int q = 0; q < NB; q++) {
      int e = q * 256 + tid;
      if (e < EB) {
        int r = e >> 2, kk = (e & 3) * 8;
        *(uint4*)&Bs[r * 40 + kk] = br[q];
      }
    }
    __syncthreads();
    // prefetch tile k+1 (in flight during ds_read + MFMA below)
    if (k0 + 32 < K) {
#pragma unroll
      for (int q = 0; q < NA; q++) {
        int e = q * 256 + tid;
        if (e < EA) {
          int r = e >> 2, kk = (e & 3) * 8;
          ar[q] = *(const uint4*)(A + (size_t)(m0 + r) * K + k0 + 32 + kk);
        }
      }
#pragma unroll
      for (int q = 0; q < NB; q++) {
        int e = q * 256 + tid;
        if (e < EB) {
          int r = e >> 2, kk = (e & 3) * 8;
          br[q] = *(const uint4*)(Bt + (size_t)(n0 + r) * K + k0 + 32 + kk);
        }
      }
    }
    bf16x8 af[FI], bfr[FJ];
#pragma unroll
    for (int i = 0; i < FI; i++)
      af[i] = *(const bf16x8*)&As[(wm + i * 16 + fm) * 40 + fq * 8];
#pragma unroll
    for (int j = 0; j < FJ; j++)
      bfr[j] = *(const bf16x8*)&Bs[(wn + j * 16 + fm) * 40 + fq * 8];
#pragma unroll
    for (int i = 0; i < FI; i++)
#pragma unroll
      for (int j = 0; j < FJ; j++)
        acc[i][j] = __builtin_amdgcn_mfma_f32_16x16x32_bf16(af[i], bfr[j], acc[i][j], 0, 0, 0);
  }
  // C store
#pragma unroll
  for (int i = 0; i < FI; i++) {
#pragma unroll
    for (int j = 0; j < FJ; j++) {
      int r = m0 + wm + i * 16 + fq * 4;
      int ccol = n0 + wn + j * 16 + fm;
#pragma unroll
      for (int reg = 0; reg < 4; reg++)
        C[(size_t)(r + reg) * N + ccol] = acc[i][j][reg];
    }
  }
  // fused s/t epilogue
  {
    int hh = n0 >> 7;
    float avs[FJ], avd[FJ];
#pragma unroll
    for (int j = 0; j < FJ; j++) {
      int col = n0 + wn + j * 16 + fm;
      avs[j] = av_s[col];
      avd[j] = av_d[col];
    }
#pragma unroll
    for (int i = 0; i < FI; i++) {
#pragma unroll
      for (int reg = 0; reg < 4; reg++) {
        float sv = 0.f, tv = 0.f;
#pragma unroll
        for (int j = 0; j < FJ; j++) {
          sv = fmaf(acc[i][j][reg], avs[j], sv);
          tv = fmaf(acc[i][j][reg], avd[j], tv);
        }
#pragma unroll
        for (int o = 1; o < 16; o <<= 1) {
          sv += __shfl_xor(sv, o, 64);
          tv += __shfl_xor(tv, o, 64);
        }
        if (fm == 0) {
          int row = m0 + wm + i * 16 + fq * 4 + reg;
          atomicAdd(&sAcc[(size_t)hh * NNODE + row], sv);
          atomicAdd(&tAcc[(size_t)hh * NNODE + row], tv);
        }
      }
    }
  }
}

// One-kernel rank sort + query split precompute. All 4096 keys in LDS.
// ALSO counts lo[n] = #{j : s_j < -t_n} (strict <, == lower_bound).
__global__ __launch_bounds__(256) void rank_sort_kernel(const float* __restrict__ s,
                                                        const float* __restrict__ t,
                                                        float* __restrict__ ss,
                                                        int* __restrict__ si,
                                                        int* __restrict__ qlo) {
  __shared__ __align__(16) float keys[NNODE];
  __shared__ int pc[8][32], qc[8][32];
  int hh = blockIdx.y, tid = threadIdx.x;
  const float* sp = s + (size_t)hh * NNODE;
  for (int k = tid; k < NNODE / 4; k += 256)
    ((float4*)keys)[k] = ((const float4*)sp)[k];
  __syncthreads();
  int slot = tid & 31, part = tid >> 5;
  int node = blockIdx.x * 32 + slot;
  float mk = keys[node];
  float qk = -t[(size_t)hh * NNODE + node];
  int cnt = 0, cq = 0;
  int j0 = part * 512;
#pragma unroll 4
  for (int j = j0; j < j0 + 512; j += 4) {
    float4 kv = *(const float4*)&keys[j];
    cnt += (kv.x < mk) || (kv.x == mk && (j + 0) < node);
    cnt += (kv.y < mk) || (kv.y == mk && (j + 1) < node);
    cnt += (kv.z < mk) || (kv.z == mk && (j + 2) < node);
    cnt += (kv.w < mk) || (kv.w == mk && (j + 3) < node);
    cq += (kv.x < qk) + (kv.y < qk) + (kv.z < qk) + (kv.w < qk);
  }
  pc[part][slot] = cnt;
  qc[part][slot] = cq;
  __syncthreads();
  if (tid < 32) {
    int rank = 0;
#pragma unroll
    for (int p = 0; p < 8; p++) rank += pc[p][tid];
    int n2 = blockIdx.x * 32 + tid;
    ss[(size_t)hh * NNODE + rank] = keys[n2];
    si[(size_t)hh * NNODE + rank] = n2;
  } else if (tid < 64) {
    int sl = tid - 32;
    int lo = 0;
#pragma unroll
    for (int p = 0; p < 8; p++) lo += qc[p][sl];
    qlo[(size_t)hh * NNODE + blockIdx.x * 32 + sl] = lo;
  }
}

// Pass A: per-chunk partial sums of e^{s}*h (P) and e^{0.2s}*h (M); z at 128.
__global__ __launch_bounds__(128) void passA_kernel(const float* __restrict__ h,
                                                    const float* __restrict__ ss,
                                                    const int* __restrict__ si,
                                                    float* __restrict__ partP,
                                                    float* __restrict__ partM, int H) {
  __shared__ float eP[CHUNK], eM[CHUNK];
  __shared__ int ids[CHUNK];
  int b = blockIdx.x, hh = b / NCHUNK, ci = b % NCHUNK;
  int c = threadIdx.x;
  int HC = H * CDIM;
  int base = ci * CHUNK;
  if (c < CHUNK) {
    float sv = ss[(size_t)hh * NNODE + base + c];
    ids[c] = si[(size_t)hh * NNODE + base + c];
    eP[c] = expf(sv);
    eM[c] = expf(NEG * sv);
  }
  __syncthreads();
  float sp = 0.f, sm = 0.f;
  for (int kb = 0; kb < CHUNK; kb += 8) {
    float v[8];
#pragma unroll
    for (int j = 0; j < 8; j++)
      v[j] = h[(size_t)ids[kb + j] * HC + hh * CDIM + c];
#pragma unroll
    for (int j = 0; j < 8; j++) {
      sp = fmaf(eP[kb + j], v[j], sp);
      sm = fmaf(eM[kb + j], v[j], sm);
    }
  }
  size_t o = ((size_t)hh * NCHUNK + ci) * TW;
  partP[o + c] = sp;
  partM[o + c] = sm;
  if (c == 0) {
    float zp = 0.f, zm = 0.f;
#pragma unroll
    for (int k = 0; k < CHUNK; k++) { zp += eP[k]; zm += eM[k]; }
    partP[o + 128] = zp;
    partM[o + 128] = zm;
  }
}

// Pass B, grid (3, H): dir 0 = exclusive prefix of partM; dir 1 = exclusive
// suffix of partP; dir 2 = bucket queries by split chunk (counting scatter).
__global__ __launch_bounds__(192) void passB_kernel(const float* __restrict__ partP,
                                                    const float* __restrict__ partM,
                                                    float* __restrict__ sufP,
                                                    float* __restrict__ prefM,
                                                    const int* __restrict__ qlo,
                                                    int* __restrict__ qbuf,
                                                    int* __restrict__ qoff) {
  __shared__ int hist[NCHUNK];
  __shared__ int offs[NCHUNK + 1];
  int hh = blockIdx.y, dir = blockIdx.x;
  int c = threadIdx.x;
  if (dir == 2) {  // bucket: counting sort of queries by lo>>5
    const int* ql = qlo + (size_t)hh * NNODE;
    for (int i = c; i < NCHUNK; i += 192) hist[i] = 0;
    __syncthreads();
    for (int i = c; i < NNODE; i += 192) {
      int bin = ql[i] >> 5; bin = bin > NCHUNK - 1 ? NCHUNK - 1 : bin;
      atomicAdd(&hist[bin], 1);
    }
    __syncthreads();
    if (c == 0) {
      int run = 0;
      for (int k = 0; k < NCHUNK; k++) { offs[k] = run; run += hist[k]; }
      offs[NCHUNK] = run;
    }
    __syncthreads();
    for (int i = c; i <= NCHUNK; i += 192) qoff[hh * (NCHUNK + 1) + i] = offs[i];
    for (int i = c; i < NCHUNK; i += 192) hist[i] = offs[i];
    __syncthreads();
    for (int i = c; i < NNODE; i += 192) {
      int bin = ql[i] >> 5; bin = bin > NCHUNK - 1 ? NCHUNK - 1 : bin;
      int pos = atomicAdd(&hist[bin], 1);
      qbuf[(size_t)hh * NNODE + pos] = i;
    }
    return;
  }
  if (c > 128) return;  // 129 cols: 128 features + z
  size_t base = (size_t)hh * NCHUNK * TW;
  if (dir == 0) {  // forward exclusive prefix of partM
    float run = 0.f;
    for (int g0 = 0; g0 < NCHUNK; g0 += 8) {
      float v[8];
#pragma unroll
      for (int j = 0; j < 8; j++) v[j] = partM[base + (size_t)(g0 + j) * TW + c];
#pragma unroll
      for (int j = 0; j < 8; j++) {
        prefM[base + (size_t)(g0 + j) * TW + c] = run;
        run += v[j];
      }
    }
  } else {  // backward exclusive suffix of partP
    float run = 0.f;
    for (int g0 = NCHUNK - 8; g0 >= 0; g0 -= 8) {
      float v[8];
#pragma unroll
      for (int j = 7; j >= 0; j--) v[j] = partP[base + (size_t)(g0 + j) * TW + c];
#pragma unroll
      for (int j = 7; j >= 0; j--) {
        sufP[base + (size_t)(g0 + j) * TW + c] = run;
        run += v[j];
      }
    }
  }
}

// Pass D: one block per chunk. Stage the chunk's 32 e*h rows in LDS, then
// answer every query whose split lands in this chunk: prefix (k<loc, asc)
// with eM, suffix (31..loc, desc) with eP -- same order as the old table
// scan -- plus the passB carries, bias, ELU. 2 queries in flight (halves).
template <typename OUT>
__global__ __launch_bounds__(256) void passD_kernel(const float* __restrict__ h,
                                                    const float* __restrict__ ss,
                                                    const int* __restrict__ si,
                                                    const int* __restrict__ qlo,
                                                    const int* __restrict__ qbuf,
                                                    const int* __restrict__ qoff,
                                                    const float* __restrict__ fP,
                                                    const float* __restrict__ fM,
                                                    const float* __restrict__ tt,
                                                    const float* __restrict__ bias,
                                                    OUT* __restrict__ out, int H) {
  __shared__ float hrow[CHUNK][CDIM];  // 16 KB
  __shared__ float eP[CHUNK], eM[CHUNK];
  __shared__ int ids[CHUNK];
  int b = blockIdx.x, hh = b / NCHUNK, ci = b % NCHUNK;
  int tid = threadIdx.x;
  int qbase = qoff[hh * (NCHUNK + 1) + ci];
  int qcnt = qoff[hh * (NCHUNK + 1) + ci + 1] - qbase;
  if (qcnt == 0) return;
  int c = tid & 127, half = tid >> 7;
  int HC = H * CDIM;
  int base = ci * CHUNK;
  if (tid < CHUNK) {
    float sv = ss[(size_t)hh * NNODE + base + tid];
    ids[tid] = si[(size_t)hh * NNODE + base + tid];
    eP[tid] = expf(sv);
    eM[tid] = expf(NEG * sv);
  }
  __syncthreads();
  // gather h rows (half 0: rows 0..15, half 1: rows 16..31)
  for (int kb = half * 16; kb < half * 16 + 16; kb += 8) {
    float v[8];
#pragma unroll
    for (int j = 0; j < 8; j++)
      v[j] = h[(size_t)ids[kb + j] * HC + hh * CDIM + c];
#pragma unroll
    for (int j = 0; j < 8; j++) hrow[kb + j][c] = v[j];
  }
  __syncthreads();
  // chunk carries (uniform per block; L2-cached)
  size_t co = ((size_t)hh * NCHUNK + ci) * TW;
  float rfP = fP[co + c], rfM = fM[co + c];
  float rfPz = fP[co + 128], rfMz = fM[co + 128];
  const float* tp = tt + (size_t)hh * NNODE;
  const int* qp = qbuf + (size_t)hh * NNODE + qbase;
  const int* lp = qlo + (size_t)hh * NNODE;
  for (int it = half; it < qcnt; it += 2) {
    int n = qp[it];
    float tv = tp[n];
    int loc = lp[n] - base;  // in [0, 32]
    // prefix of eM*h over k < loc (ascending, same order as old scan)
    float pm = 0.f, zm = 0.f;
    for (int k = 0; k < loc; k++) {
      pm = fmaf(eM[k], hrow[k][c], pm);
      zm += eM[k];
    }
    // suffix of eP*h over k >= loc (descending, same order as old scan)
    float pp = 0.f, zp = 0.f;
    for (int k = CHUNK - 1; k >= loc; k--) {
      pp = fmaf(eP[k], hrow[k][c], pp);
      zp += eP[k];
    }
    float wp = expf(tv), wm = expf(NEG * tv);
    float num = wp * (pp + rfP) + wm * (pm + rfM);
    float Z = wp * (zp + rfPz) + wm * (zm + rfMz);
    float ov = num / Z + bias[hh * CDIM + c];
    float r = (ov > 0.f) ? ov : (expf(ov) - 1.f);
    if constexpr (sizeof(OUT) == 2)
      out[(size_t)n * HC + hh * CDIM + c] = f2b(r);
    else
      out[(size_t)n * HC + hh * CDIM + c] = r;
  }
}

// Coalesced column partial sums: block b sums rows [b*64, b*64+64) into
// part[b][128]. float4 loads, LDS tree over row-groups. No atomics.
__global__ __launch_bounds__(256) void mean_part_kernel(const float* __restrict__ x,
                                                        float* __restrict__ part) {
  __shared__ float4 red[256];
  int b = blockIdx.x, tid = threadIdx.x;
  int q = tid & 31, r0 = tid >> 5;  // q: col quad (4 cols), r0: row group
  const float4* xp = (const float4*)x;
  float4 s = {0.f, 0.f, 0.f, 0.f};
  int base = b * 64;
  for (int r = r0; r < 64; r += 8) {
    float4 v = xp[(size_t)(base + r) * 32 + q];
    s.x += v.x; s.y += v.y; s.z += v.z; s.w += v.w;
  }
  red[tid] = s; __syncthreads();
  for (int off = 4; off > 0; off >>= 1) {
    if (r0 < off) {
      float4 o = red[tid + off * 32];
      red[tid].x += o.x; red[tid].y += o.y; red[tid].z += o.z; red[tid].w += o.w;
    }
    __syncthreads();
  }
  if (tid < 32) ((float4*)part)[b * 32 + tid] = red[tid];
}

// Reduce the 64x128 partials (redundantly per block, trivial) then GEMV.
__global__ __launch_bounds__(256) void fc_kernel(const float* __restrict__ part,
                                                 const float* __restrict__ fcW,
                                                 const float* __restrict__ fcb,
                                                 float* __restrict__ out) {
  __shared__ float tmp[256];
  __shared__ float m[CDIM];
  int tid = threadIdx.x;
  int c = tid & 127, half = tid >> 7;
  float a = 0.f;
  for (int g = half; g < 64; g += 2) a += part[g * CDIM + c];
  tmp[tid] = a; __syncthreads();
  if (tid < 128) m[tid] = (tmp[tid] + tmp[tid + 128]) * (1.f / NNODE);
  __syncthreads();
  int d = blockIdx.x * 256 + tid;  // 768 total
  float acc = fcb[d];
#pragma unroll 4
  for (int c2 = 0; c2 < CDIM; c2++) acc = fmaf(m[c2], fcW[c2 * 768 + d], acc);
  out[d] = acc;
}

extern "C" void kernel_launch(void* const* d_in, const int* in_sizes, int n_in,
                              void* d_out, int out_size, void* d_ws, size_t ws_size,
                              hipStream_t stream) {
  const float* x   = (const float*)d_in[0];
  const float* W1  = (const float*)d_in[1];
  const float* as1 = (const float*)d_in[2];
  const float* ad1 = (const float*)d_in[3];
  const float* b1  = (const float*)d_in[4];
  const float* W2  = (const float*)d_in[5];
  const float* as2 = (const float*)d_in[6];
  const float* ad2 = (const float*)d_in[7];
  const float* b2  = (const float*)d_in[8];
  const float* fcW = (const float*)d_in[9];
  const float* fcb = (const float*)d_in[10];

  float* ws = (float*)d_ws;
  size_t off = 0;
  auto alloc = [&](size_t nfloats) { float* p = ws + off; off += nfloats; return p; };

  float* h1  = alloc((size_t)NNODE * 512);
  float* x2f = alloc((size_t)NNODE * 256 + 64 + 16384);  // x2b bf16 + W2t bf16
  float* h2  = alloc((size_t)NNODE * 128);
  float* x3  = alloc((size_t)NNODE * 128);
  float* xbf = alloc((size_t)NNODE * 384);   // x bf16 4096x768
  float* w1f = alloc((size_t)512 * 384);     // W1t bf16 512x768
  float* s1  = alloc((size_t)4 * NNODE);
  float* t1  = alloc((size_t)4 * NNODE);
  float* sS1 = alloc((size_t)4 * NNODE);
  int*   sI1 = (int*)alloc((size_t)4 * NNODE);
  int*   qL1 = (int*)alloc((size_t)4 * NNODE);
  int*   qB1 = (int*)alloc((size_t)4 * NNODE);
  int*   qO1 = (int*)alloc((size_t)4 * (NCHUNK + 1));
  float* pP1 = alloc((size_t)4 * NCHUNK * TW);
  float* pM1 = alloc((size_t)4 * NCHUNK * TW);
  float* fP1 = alloc((size_t)4 * NCHUNK * TW);   // chunk suffix of P
  float* fM1 = alloc((size_t)4 * NCHUNK * TW);   // chunk prefix of M
  float* s2  = alloc(NNODE);
  float* t2  = alloc(NNODE);
  float* sS2 = alloc(NNODE);
  int*   sI2 = (int*)alloc(NNODE);
  int*   qL2 = (int*)alloc(NNODE);
  int*   qB2 = (int*)alloc(NNODE);
  int*   qO2 = (int*)alloc(NCHUNK + 1);
  float* pP2 = alloc((size_t)NCHUNK * TW);
  float* pM2 = alloc((size_t)NCHUNK * TW);
  float* fP2 = alloc((size_t)NCHUNK * TW);
  float* fM2 = alloc((size_t)NCHUNK * TW);
  float* mpart = alloc((size_t)64 * CDIM);  // mean partial sums

  unsigned short* xb  = (unsigned short*)xbf;
  unsigned short* W1t = (unsigned short*)w1f;
  unsigned short* x2b = (unsigned short*)x2f;                       // 4096x512 bf16
  unsigned short* W2t = (unsigned short*)(x2f + NNODE * 256 + 64);  // 128x512 bf16

  // Prep: convert x + transpose/cast W1, W2 + zero s/t accumulators
  prep_kernel<<<3224, 256, 0, stream>>>(x, W1, W2, xb, W1t, W2t, s1, s2);
  // Layer 1 (fused s/t epilogue)
  mfma_gemm_bt<64, 64><<<dim3(512 / 64, NNODE / 64), 256, 0, stream>>>(
      xb, W1t, h1, NNODE, 512, 768, s1, t1, as1, ad1);
  rank_sort_kernel<<<dim3(NNODE / 32, 4), 256, 0, stream>>>(s1, t1, sS1, sI1, qL1);
  passA_kernel<<<4 * NCHUNK, 128, 0, stream>>>(h1, sS1, sI1, pP1, pM1, 4);
  passB_kernel<<<dim3(3, 4), 192, 0, stream>>>(pP1, pM1, fP1, fM1, qL1, qB1, qO1);
  passD_kernel<unsigned short><<<4 * NCHUNK, 256, 0, stream>>>(
      h1, sS1, sI1, qL1, qB1, qO1, fP1, fM1, t1, b1, x2b, 4);
  // Layer 2 (fused s/t epilogue)
  mfma_gemm_bt<32, 64><<<dim3(128 / 64, NNODE / 32), 256, 0, stream>>>(
      x2b, W2t, h2, NNODE, 128, 512, s2, t2, as2, ad2);
  rank_sort_kernel<<<dim3(NNODE / 32, 1), 256, 0, stream>>>(s2, t2, sS2, sI2, qL2);
  passA_kernel<<<NCHUNK, 128, 0, stream>>>(h2, sS2, sI2, pP2, pM2, 1);
  passB_kernel<<<dim3(3, 1), 192, 0, stream>>>(pP2, pM2, fP2, fM2, qL2, qB2, qO2);
  passD_kernel<float><<<NCHUNK, 256, 0, stream>>>(
      h2, sS2, sI2, qL2, qB2, qO2, fP2, fM2, t2, b2, x3, 1);
  // Readout: coalesced mean partials + fc
  mean_part_kernel<<<64, 256, 0, stream>>>(x3, mpart);
  fc_kernel<<<3, 256, 0, stream>>>(mpart, fcW, fcb, (float*)d_out);
}

// Round 7
// 280.833 us; speedup vs baseline: 6.7916x; 6.7916x over previous
//
#include <hip/hip_runtime.h>
#include <hip/hip_bf16.h>

// FacePartGAT: dense-graph GATConv x2 + mean + fc on MI355X. ALL I/O fp32.
// e[i,j] = leaky_relu(t_i + s_j) => softmax aggregation factorizes after
// sorting sources by s_j. Exact.
// Round 18: fix R17's passD load imbalance. The split distribution is
// data-dependent and EXTREMELY skewed in layer 2 (attention averages all
// sources -> near-identical rows -> all 4096 splits in ONE chunk -> one
// block ran 1665us at 0.05% occupancy). passD now parallelizes over
// QUERIES: each block owns 32 consecutive bucketed queries (balanced by
// construction), prestages their metadata in LDS (one parallel round),
// and walks chunk-runs within its slice (<=2 stages typical, all blocks
// stage the same L2-hot chunk in the skewed case). Same accumulation
// order as the table scan -> absmax unchanged.

#define NNODE 4096
#define CDIM 128
#define TW 132           // partial-table width: 128 features + z at col 128
#define NEG 0.2f
#define CHUNK 32
#define NCHUNK 128       // NNODE / CHUNK

typedef __bf16 bf16x8 __attribute__((ext_vector_type(8)));
typedef float f32x4 __attribute__((ext_vector_type(4)));

__device__ __forceinline__ unsigned short f2b(float f) {
  unsigned int u = __float_as_uint(f);
  u += 0x7fffu + ((u >> 16) & 1u);  // RTNE
  return (unsigned short)(u >> 16);
}

// One kernel: [0,3072) convert x -> bf16; [3072,3168) W1 transpose;
// [3168,3184) W2 transpose; [3184,3216) zero s1/t1; [3216,3224) zero s2/t2.
__global__ __launch_bounds__(256) void prep_kernel(const float* __restrict__ x,
                                                   const float* __restrict__ W1,
                                                   const float* __restrict__ W2,
                                                   unsigned short* __restrict__ xb,
                                                   unsigned short* __restrict__ W1t,
                                                   unsigned short* __restrict__ W2t,
                                                   float* __restrict__ zs1,
                                                   float* __restrict__ zs2) {
  __shared__ float tile[64][65];
  int b = blockIdx.x, t = threadIdx.x;
  if (b < 3072) {  // convert x: 4096*768/4 quads
    int i = b * 256 + t;
    float4 v = ((const float4*)x)[i];
    ushort4 o;
    o.x = f2b(v.x); o.y = f2b(v.y); o.z = f2b(v.z); o.w = f2b(v.w);
    ((ushort4*)xb)[i] = o;
    return;
  }
  if (b >= 3184) {  // zero s/t accumulators
    float4 z = {0.f, 0.f, 0.f, 0.f};
    if (b < 3216) {
      ((float4*)zs1)[(b - 3184) * 256 + t] = z;       // s1+t1: 32768 floats
    } else {
      ((float4*)zs2)[(b - 3216) * 256 + t] = z;       // s2+t2: 8192 floats
    }
    return;
  }
  const float* W; unsigned short* Wt; int K, N, n0, k0;
  if (b < 3072 + 96) {  // W1 [768,512] -> W1t [512,768]
    int b2 = b - 3072; W = W1; Wt = W1t; K = 768; N = 512;
    n0 = (b2 & 7) * 64; k0 = (b2 >> 3) * 64;
  } else {              // W2 [512,128] -> W2t [128,512]
    int b3 = b - 3072 - 96; W = W2; Wt = W2t; K = 512; N = 128;
    n0 = (b3 & 1) * 64; k0 = (b3 >> 1) * 64;
  }
  for (int p = 0; p < 16; p++) {
    int e = p * 256 + t;
    int rr = e >> 6, cc = e & 63;
    tile[rr][cc] = W[(size_t)(k0 + rr) * N + n0 + cc];
  }
  __syncthreads();
  for (int p = 0; p < 16; p++) {
    int e = p * 256 + t;
    int rr = e >> 6, cc = e & 63;  // rr: n-dir, cc: k-dir
    Wt[(size_t)(n0 + rr) * K + k0 + cc] = f2b(tile[cc][rr]);
  }
}

// C[M,N] = A[M,K] x Bt[N,K]^T, both bf16 K-contig. BK=32, 256 thr = 4 waves
// (2x2). Register prefetch of tile k+1 between LDS barrier and MFMA.
// Fused epilogue: s[h][n] / t[h][n] partial dot products from acc registers.
template <int BM, int BN>
__global__ __launch_bounds__(256) void mfma_gemm_bt(const unsigned short* __restrict__ A,
                                                    const unsigned short* __restrict__ Bt,
                                                    float* __restrict__ C,
                                                    int M, int N, int K,
                                                    float* __restrict__ sAcc,
                                                    float* __restrict__ tAcc,
                                                    const float* __restrict__ av_s,
                                                    const float* __restrict__ av_d) {
  __shared__ __align__(16) unsigned short As[BM * 40];
  __shared__ __align__(16) unsigned short Bs[BN * 40];
  constexpr int WM = BM / 2, WN = BN / 2;
  constexpr int FI = WM / 16, FJ = WN / 16;
  constexpr int EA = BM * 32 / 8;
  constexpr int EB = BN * 32 / 8;
  constexpr int NA = (EA + 255) / 256;
  constexpr int NB = (EB + 255) / 256;
  int tid = threadIdx.x;
  int lane = tid & 63, wave = tid >> 6;
  int wm = (wave >> 1) * WM, wn = (wave & 1) * WN;
  int m0 = blockIdx.y * BM, n0 = blockIdx.x * BN;
  int fm = lane & 15, fq = lane >> 4;
  f32x4 acc[FI][FJ] = {};
  uint4 ar[NA], br[NB];
  // preload tile 0
#pragma unroll
  for (int q = 0; q < NA; q++) {
    int e = q * 256 + tid;
    if (e < EA) {
      int r = e >> 2, kk = (e & 3) * 8;
      ar[q] = *(const uint4*)(A + (size_t)(m0 + r) * K + kk);
    }
  }
#pragma unroll
  for (int q = 0; q < NB; q++) {
    int e = q * 256 + tid;
    if (e < EB) {
      int r = e >> 2, kk = (e & 3) * 8;
      br[q] = *(const uint4*)(Bt + (size_t)(n0 + r) * K + kk);
    }
  }
  for (int k0 = 0; k0 < K; k0 += 32) {
    __syncthreads();  // previous iter's ds_reads done before overwrite
#pragma unroll
    for (int q = 0; q < NA; q++) {
      int e = q * 256 + tid;
      if (e < EA) {
        int r = e >> 2, kk = (e & 3) * 8;
        *(uint4*)&As[r * 40 + kk] = ar[q];
      }
    }
#pragma unroll
    for (int q = 0; q < NB; q++) {
      int e = q * 256 + tid;
      if (e < EB) {
        int r = e >> 2, kk = (e & 3) * 8;
        *(uint4*)&Bs[r * 40 + kk] = br[q];
      }
    }
    __syncthreads();
    // prefetch tile k+1 (in flight during ds_read + MFMA below)
    if (k0 + 32 < K) {
#pragma unroll
      for (int q = 0; q < NA; q++) {
        int e = q * 256 + tid;
        if (e < EA) {
          int r = e >> 2, kk = (e & 3) * 8;
          ar[q] = *(const uint4*)(A + (size_t)(m0 + r) * K + k0 + 32 + kk);
        }
      }
#pragma unroll
      for (int q = 0; q < NB; q++) {
        int e = q * 256 + tid;
        if (e < EB) {
          int r = e >> 2, kk = (e & 3) * 8;
          br[q] = *(const uint4*)(Bt + (size_t)(n0 + r) * K + k0 + 32 + kk);
        }
      }
    }
    bf16x8 af[FI], bfr[FJ];
#pragma unroll
    for (int i = 0; i < FI; i++)
      af[i] = *(const bf16x8*)&As[(wm + i * 16 + fm) * 40 + fq * 8];
#pragma unroll
    for (int j = 0; j < FJ; j++)
      bfr[j] = *(const bf16x8*)&Bs[(wn + j * 16 + fm) * 40 + fq * 8];
#pragma unroll
    for (int i = 0; i < FI; i++)
#pragma unroll
      for (int j = 0; j < FJ; j++)
        acc[i][j] = __builtin_amdgcn_mfma_f32_16x16x32_bf16(af[i], bfr[j], acc[i][j], 0, 0, 0);
  }
  // C store
#pragma unroll
  for (int i = 0; i < FI; i++) {
#pragma unroll
    for (int j = 0; j < FJ; j++) {
      int r = m0 + wm + i * 16 + fq * 4;
      int ccol = n0 + wn + j * 16 + fm;
#pragma unroll
      for (int reg = 0; reg < 4; reg++)
        C[(size_t)(r + reg) * N + ccol] = acc[i][j][reg];
    }
  }
  // fused s/t epilogue
  {
    int hh = n0 >> 7;
    float avs[FJ], avd[FJ];
#pragma unroll
    for (int j = 0; j < FJ; j++) {
      int col = n0 + wn + j * 16 + fm;
      avs[j] = av_s[col];
      avd[j] = av_d[col];
    }
#pragma unroll
    for (int i = 0; i < FI; i++) {
#pragma unroll
      for (int reg = 0; reg < 4; reg++) {
        float sv = 0.f, tv = 0.f;
#pragma unroll
        for (int j = 0; j < FJ; j++) {
          sv = fmaf(acc[i][j][reg], avs[j], sv);
          tv = fmaf(acc[i][j][reg], avd[j], tv);
        }
#pragma unroll
        for (int o = 1; o < 16; o <<= 1) {
          sv += __shfl_xor(sv, o, 64);
          tv += __shfl_xor(tv, o, 64);
        }
        if (fm == 0) {
          int row = m0 + wm + i * 16 + fq * 4 + reg;
          atomicAdd(&sAcc[(size_t)hh * NNODE + row], sv);
          atomicAdd(&tAcc[(size_t)hh * NNODE + row], tv);
        }
      }
    }
  }
}

// One-kernel rank sort + query split precompute. All 4096 keys in LDS.
// ALSO counts lo[n] = #{j : s_j < -t_n} (strict <, == lower_bound).
__global__ __launch_bounds__(256) void rank_sort_kernel(const float* __restrict__ s,
                                                        const float* __restrict__ t,
                                                        float* __restrict__ ss,
                                                        int* __restrict__ si,
                                                        int* __restrict__ qlo) {
  __shared__ __align__(16) float keys[NNODE];
  __shared__ int pc[8][32], qc[8][32];
  int hh = blockIdx.y, tid = threadIdx.x;
  const float* sp = s + (size_t)hh * NNODE;
  for (int k = tid; k < NNODE / 4; k += 256)
    ((float4*)keys)[k] = ((const float4*)sp)[k];
  __syncthreads();
  int slot = tid & 31, part = tid >> 5;
  int node = blockIdx.x * 32 + slot;
  float mk = keys[node];
  float qk = -t[(size_t)hh * NNODE + node];
  int cnt = 0, cq = 0;
  int j0 = part * 512;
#pragma unroll 4
  for (int j = j0; j < j0 + 512; j += 4) {
    float4 kv = *(const float4*)&keys[j];
    cnt += (kv.x < mk) || (kv.x == mk && (j + 0) < node);
    cnt += (kv.y < mk) || (kv.y == mk && (j + 1) < node);
    cnt += (kv.z < mk) || (kv.z == mk && (j + 2) < node);
    cnt += (kv.w < mk) || (kv.w == mk && (j + 3) < node);
    cq += (kv.x < qk) + (kv.y < qk) + (kv.z < qk) + (kv.w < qk);
  }
  pc[part][slot] = cnt;
  qc[part][slot] = cq;
  __syncthreads();
  if (tid < 32) {
    int rank = 0;
#pragma unroll
    for (int p = 0; p < 8; p++) rank += pc[p][tid];
    int n2 = blockIdx.x * 32 + tid;
    ss[(size_t)hh * NNODE + rank] = keys[n2];
    si[(size_t)hh * NNODE + rank] = n2;
  } else if (tid < 64) {
    int sl = tid - 32;
    int lo = 0;
#pragma unroll
    for (int p = 0; p < 8; p++) lo += qc[p][sl];
    qlo[(size_t)hh * NNODE + blockIdx.x * 32 + sl] = lo;
  }
}

// Pass A: per-chunk partial sums of e^{s}*h (P) and e^{0.2s}*h (M); z at 128.
__global__ __launch_bounds__(128) void passA_kernel(const float* __restrict__ h,
                                                    const float* __restrict__ ss,
                                                    const int* __restrict__ si,
                                                    float* __restrict__ partP,
                                                    float* __restrict__ partM, int H) {
  __shared__ float eP[CHUNK], eM[CHUNK];
  __shared__ int ids[CHUNK];
  int b = blockIdx.x, hh = b / NCHUNK, ci = b % NCHUNK;
  int c = threadIdx.x;
  int HC = H * CDIM;
  int base = ci * CHUNK;
  if (c < CHUNK) {
    float sv = ss[(size_t)hh * NNODE + base + c];
    ids[c] = si[(size_t)hh * NNODE + base + c];
    eP[c] = expf(sv);
    eM[c] = expf(NEG * sv);
  }
  __syncthreads();
  float sp = 0.f, sm = 0.f;
  for (int kb = 0; kb < CHUNK; kb += 8) {
    float v[8];
#pragma unroll
    for (int j = 0; j < 8; j++)
      v[j] = h[(size_t)ids[kb + j] * HC + hh * CDIM + c];
#pragma unroll
    for (int j = 0; j < 8; j++) {
      sp = fmaf(eP[kb + j], v[j], sp);
      sm = fmaf(eM[kb + j], v[j], sm);
    }
  }
  size_t o = ((size_t)hh * NCHUNK + ci) * TW;
  partP[o + c] = sp;
  partM[o + c] = sm;
  if (c == 0) {
    float zp = 0.f, zm = 0.f;
#pragma unroll
    for (int k = 0; k < CHUNK; k++) { zp += eP[k]; zm += eM[k]; }
    partP[o + 128] = zp;
    partM[o + 128] = zm;
  }
}

// Pass B, grid (3, H): dir 0 = exclusive prefix of partM; dir 1 = exclusive
// suffix of partP; dir 2 = bucket queries by split chunk (counting scatter).
__global__ __launch_bounds__(192) void passB_kernel(const float* __restrict__ partP,
                                                    const float* __restrict__ partM,
                                                    float* __restrict__ sufP,
                                                    float* __restrict__ prefM,
                                                    const int* __restrict__ qlo,
                                                    int* __restrict__ qbuf) {
  __shared__ int hist[NCHUNK];
  __shared__ int offs[NCHUNK];
  int hh = blockIdx.y, dir = blockIdx.x;
  int c = threadIdx.x;
  if (dir == 2) {  // bucket: counting sort of queries by lo>>5
    const int* ql = qlo + (size_t)hh * NNODE;
    for (int i = c; i < NCHUNK; i += 192) hist[i] = 0;
    __syncthreads();
    for (int i = c; i < NNODE; i += 192) {
      int bin = ql[i] >> 5; bin = bin > NCHUNK - 1 ? NCHUNK - 1 : bin;
      atomicAdd(&hist[bin], 1);
    }
    __syncthreads();
    if (c == 0) {
      int run = 0;
      for (int k = 0; k < NCHUNK; k++) { offs[k] = run; run += hist[k]; }
    }
    __syncthreads();
    for (int i = c; i < NCHUNK; i += 192) hist[i] = offs[i];
    __syncthreads();
    for (int i = c; i < NNODE; i += 192) {
      int bin = ql[i] >> 5; bin = bin > NCHUNK - 1 ? NCHUNK - 1 : bin;
      int pos = atomicAdd(&hist[bin], 1);
      qbuf[(size_t)hh * NNODE + pos] = i;
    }
    return;
  }
  if (c > 128) return;  // 129 cols: 128 features + z
  size_t base = (size_t)hh * NCHUNK * TW;
  if (dir == 0) {  // forward exclusive prefix of partM
    float run = 0.f;
    for (int g0 = 0; g0 < NCHUNK; g0 += 8) {
      float v[8];
#pragma unroll
      for (int j = 0; j < 8; j++) v[j] = partM[base + (size_t)(g0 + j) * TW + c];
#pragma unroll
      for (int j = 0; j < 8; j++) {
        prefM[base + (size_t)(g0 + j) * TW + c] = run;
        run += v[j];
      }
    }
  } else {  // backward exclusive suffix of partP
    float run = 0.f;
    for (int g0 = NCHUNK - 8; g0 >= 0; g0 -= 8) {
      float v[8];
#pragma unroll
      for (int j = 7; j >= 0; j--) v[j] = partP[base + (size_t)(g0 + j) * TW + c];
#pragma unroll
      for (int j = 7; j >= 0; j--) {
        sufP[base + (size_t)(g0 + j) * TW + c] = run;
        run += v[j];
      }
    }
  }
}

// Pass D v2 (query-parallel, skew-proof): block owns 32 consecutive
// bucketed queries. Prestage metadata (n, lo, t) in one parallel round;
// walk chunk-runs: stage run's chunk (32 e*h rows in LDS), evaluate
// queries pairwise (halves). Same accumulation order as the table scan
// (prefix asc with eM, suffix desc with eP) + passB carries, bias, ELU.
template <typename OUT>
__global__ __launch_bounds__(256) void passD_kernel(const float* __restrict__ h,
                                                    const float* __restrict__ ss,
                                                    const int* __restrict__ si,
                                                    const int* __restrict__ qlo,
                                                    const int* __restrict__ qbuf,
                                                    const float* __restrict__ fP,
                                                    const float* __restrict__ fM,
                                                    const float* __restrict__ tt,
                                                    const float* __restrict__ bias,
                                                    OUT* __restrict__ out, int H) {
  __shared__ float hrow[CHUNK][CDIM];  // 16 KB
  __shared__ float eP[CHUNK], eM[CHUNK];
  __shared__ int ids[CHUNK];
  __shared__ int qn[32], qL[32];
  __shared__ float qt[32];
  int b = blockIdx.x;
  int hh = b >> 7, qb = (b & 127) * 32;  // grid = H * 128
  int tid = threadIdx.x;
  int c = tid & 127, half = tid >> 7;
  int HC = H * CDIM;
  // prestage query metadata (one parallel scattered round)
  if (tid < 32) {
    int n = qbuf[(size_t)hh * NNODE + qb + tid];
    qn[tid] = n;
    qL[tid] = qlo[(size_t)hh * NNODE + n];
    qt[tid] = tt[(size_t)hh * NNODE + n];
  }
  __syncthreads();
  float bv = bias[hh * CDIM + c];
  int it = 0;
  while (it < 32) {
    int lo0 = qL[it];
    int ci = lo0 >> 5; if (ci > NCHUNK - 1) ci = NCHUNK - 1;
    int ie = it + 1;
    while (ie < 32) {
      int cj = qL[ie] >> 5; if (cj > NCHUNK - 1) cj = NCHUNK - 1;
      if (cj != ci) break;
      ie++;
    }
    int base = ci * CHUNK;
    __syncthreads();  // protect previous run's LDS reads
    if (tid < CHUNK) {
      float sv = ss[(size_t)hh * NNODE + base + tid];
      ids[tid] = si[(size_t)hh * NNODE + base + tid];
      eP[tid] = expf(sv);
      eM[tid] = expf(NEG * sv);
    }
    __syncthreads();
    // gather chunk rows (half 0: rows 0..15, half 1: rows 16..31)
    for (int kb = half * 16; kb < half * 16 + 16; kb += 8) {
      float v[8];
#pragma unroll
      for (int j = 0; j < 8; j++)
        v[j] = h[(size_t)ids[kb + j] * HC + hh * CDIM + c];
#pragma unroll
      for (int j = 0; j < 8; j++) hrow[kb + j][c] = v[j];
    }
    __syncthreads();
    size_t co = ((size_t)hh * NCHUNK + ci) * TW;
    float rfP = fP[co + c], rfM = fM[co + c];
    float rfPz = fP[co + 128], rfMz = fM[co + 128];
    for (int q = it + half; q < ie; q += 2) {
      int n = qn[q];
      float tv = qt[q];
      int loc = qL[q] - base;  // in [0, 32]
      float pm = 0.f, zm = 0.f;
      for (int k = 0; k < loc; k++) {
        pm = fmaf(eM[k], hrow[k][c], pm);
        zm += eM[k];
      }
      float pp = 0.f, zp = 0.f;
      for (int k = CHUNK - 1; k >= loc; k--) {
        pp = fmaf(eP[k], hrow[k][c], pp);
        zp += eP[k];
      }
      float wp = expf(tv), wm = expf(NEG * tv);
      float num = wp * (pp + rfP) + wm * (pm + rfM);
      float Z = wp * (zp + rfPz) + wm * (zm + rfMz);
      float ov = num / Z + bv;
      float r = (ov > 0.f) ? ov : (expf(ov) - 1.f);
      if constexpr (sizeof(OUT) == 2)
        out[(size_t)n * HC + hh * CDIM + c] = f2b(r);
      else
        out[(size_t)n * HC + hh * CDIM + c] = r;
    }
    it = ie;
  }
}

// Coalesced column partial sums: block b sums rows [b*64, b*64+64) into
// part[b][128]. float4 loads, LDS tree over row-groups. No atomics.
__global__ __launch_bounds__(256) void mean_part_kernel(const float* __restrict__ x,
                                                        float* __restrict__ part) {
  __shared__ float4 red[256];
  int b = blockIdx.x, tid = threadIdx.x;
  int q = tid & 31, r0 = tid >> 5;  // q: col quad (4 cols), r0: row group
  const float4* xp = (const float4*)x;
  float4 s = {0.f, 0.f, 0.f, 0.f};
  int base = b * 64;
  for (int r = r0; r < 64; r += 8) {
    float4 v = xp[(size_t)(base + r) * 32 + q];
    s.x += v.x; s.y += v.y; s.z += v.z; s.w += v.w;
  }
  red[tid] = s; __syncthreads();
  for (int off = 4; off > 0; off >>= 1) {
    if (r0 < off) {
      float4 o = red[tid + off * 32];
      red[tid].x += o.x; red[tid].y += o.y; red[tid].z += o.z; red[tid].w += o.w;
    }
    __syncthreads();
  }
  if (tid < 32) ((float4*)part)[b * 32 + tid] = red[tid];
}

// Reduce the 64x128 partials (redundantly per block, trivial) then GEMV.
__global__ __launch_bounds__(256) void fc_kernel(const float* __restrict__ part,
                                                 const float* __restrict__ fcW,
                                                 const float* __restrict__ fcb,
                                                 float* __restrict__ out) {
  __shared__ float tmp[256];
  __shared__ float m[CDIM];
  int tid = threadIdx.x;
  int c = tid & 127, half = tid >> 7;
  float a = 0.f;
  for (int g = half; g < 64; g += 2) a += part[g * CDIM + c];
  tmp[tid] = a; __syncthreads();
  if (tid < 128) m[tid] = (tmp[tid] + tmp[tid + 128]) * (1.f / NNODE);
  __syncthreads();
  int d = blockIdx.x * 256 + tid;  // 768 total
  float acc = fcb[d];
#pragma unroll 4
  for (int c2 = 0; c2 < CDIM; c2++) acc = fmaf(m[c2], fcW[c2 * 768 + d], acc);
  out[d] = acc;
}

extern "C" void kernel_launch(void* const* d_in, const int* in_sizes, int n_in,
                              void* d_out, int out_size, void* d_ws, size_t ws_size,
                              hipStream_t stream) {
  const float* x   = (const float*)d_in[0];
  const float* W1  = (const float*)d_in[1];
  const float* as1 = (const float*)d_in[2];
  const float* ad1 = (const float*)d_in[3];
  const float* b1  = (const float*)d_in[4];
  const float* W2  = (const float*)d_in[5];
  const float* as2 = (const float*)d_in[6];
  const float* ad2 = (const float*)d_in[7];
  const float* b2  = (const float*)d_in[8];
  const float* fcW = (const float*)d_in[9];
  const float* fcb = (const float*)d_in[10];

  float* ws = (float*)d_ws;
  size_t off = 0;
  auto alloc = [&](size_t nfloats) { float* p = ws + off; off += nfloats; return p; };

  float* h1  = alloc((size_t)NNODE * 512);
  float* x2f = alloc((size_t)NNODE * 256 + 64 + 16384);  // x2b bf16 + W2t bf16
  float* h2  = alloc((size_t)NNODE * 128);
  float* x3  = alloc((size_t)NNODE * 128);
  float* xbf = alloc((size_t)NNODE * 384);   // x bf16 4096x768
  float* w1f = alloc((size_t)512 * 384);     // W1t bf16 512x768
  float* s1  = alloc((size_t)4 * NNODE);
  float* t1  = alloc((size_t)4 * NNODE);
  float* sS1 = alloc((size_t)4 * NNODE);
  int*   sI1 = (int*)alloc((size_t)4 * NNODE);
  int*   qL1 = (int*)alloc((size_t)4 * NNODE);
  int*   qB1 = (int*)alloc((size_t)4 * NNODE);
  float* pP1 = alloc((size_t)4 * NCHUNK * TW);
  float* pM1 = alloc((size_t)4 * NCHUNK * TW);
  float* fP1 = alloc((size_t)4 * NCHUNK * TW);   // chunk suffix of P
  float* fM1 = alloc((size_t)4 * NCHUNK * TW);   // chunk prefix of M
  float* s2  = alloc(NNODE);
  float* t2  = alloc(NNODE);
  float* sS2 = alloc(NNODE);
  int*   sI2 = (int*)alloc(NNODE);
  int*   qL2 = (int*)alloc(NNODE);
  int*   qB2 = (int*)alloc(NNODE);
  float* pP2 = alloc((size_t)NCHUNK * TW);
  float* pM2 = alloc((size_t)NCHUNK * TW);
  float* fP2 = alloc((size_t)NCHUNK * TW);
  float* fM2 = alloc((size_t)NCHUNK * TW);
  float* mpart = alloc((size_t)64 * CDIM);  // mean partial sums

  unsigned short* xb  = (unsigned short*)xbf;
  unsigned short* W1t = (unsigned short*)w1f;
  unsigned short* x2b = (unsigned short*)x2f;                       // 4096x512 bf16
  unsigned short* W2t = (unsigned short*)(x2f + NNODE * 256 + 64);  // 128x512 bf16

  // Prep: convert x + transpose/cast W1, W2 + zero s/t accumulators
  prep_kernel<<<3224, 256, 0, stream>>>(x, W1, W2, xb, W1t, W2t, s1, s2);
  // Layer 1 (fused s/t epilogue)
  mfma_gemm_bt<64, 64><<<dim3(512 / 64, NNODE / 64), 256, 0, stream>>>(
      xb, W1t, h1, NNODE, 512, 768, s1, t1, as1, ad1);
  rank_sort_kernel<<<dim3(NNODE / 32, 4), 256, 0, stream>>>(s1, t1, sS1, sI1, qL1);
  passA_kernel<<<4 * NCHUNK, 128, 0, stream>>>(h1, sS1, sI1, pP1, pM1, 4);
  passB_kernel<<<dim3(3, 4), 192, 0, stream>>>(pP1, pM1, fP1, fM1, qL1, qB1);
  passD_kernel<unsigned short><<<4 * 128, 256, 0, stream>>>(
      h1, sS1, sI1, qL1, qB1, fP1, fM1, t1, b1, x2b, 4);
  // Layer 2 (fused s/t epilogue)
  mfma_gemm_bt<32, 64><<<dim3(128 / 64, NNODE / 32), 256, 0, stream>>>(
      x2b, W2t, h2, NNODE, 128, 512, s2, t2, as2, ad2);
  rank_sort_kernel<<<dim3(NNODE / 32, 1), 256, 0, stream>>>(s2, t2, sS2, sI2, qL2);
  passA_kernel<<<NCHUNK, 128, 0, stream>>>(h2, sS2, sI2, pP2, pM2, 1);
  passB_kernel<<<dim3(3, 1), 192, 0, stream>>>(pP2, pM2, fP2, fM2, qL2, qB2);
  passD_kernel<float><<<128, 256, 0, stream>>>(
      h2, sS2, sI2, qL2, qB2, fP2, fM2, t2, b2, x3, 1);
  // Readout: coalesced mean partials + fc
  mean_part_kernel<<<64, 256, 0, stream>>>(x3, mpart);
  fc_kernel<<<3, 256, 0, stream>>>(mpart, fcW, fcb, (float*)d_out);
}

// Round 8
// 244.737 us; speedup vs baseline: 7.7933x; 1.1475x over previous
//
#include <hip/hip_runtime.h>
#include <hip/hip_bf16.h>

// FacePartGAT: dense-graph GATConv x2 + mean + fc on MI355X. ALL I/O fp32.
// e[i,j] = leaky_relu(t_i + s_j) => softmax aggregation factorizes after
// sorting sources by s_j. Exact.
// Round 19: fix R18's 32x redundant compute in passD. Per chunk-run the
// prefix/suffix tables are built ONCE in LDS (half 0: eM-prefix asc,
// half 1: eP-suffix desc -- concurrently, same accumulation order as the
// R16 table scan -> absmax unchanged); each query then costs 2 LDS row
// reads + carries. No global table round-trip (vs R16: -21.6 MB write,
// -43 MB read), no per-query rescan (vs R18: 1024 -> 64 serial steps).
// Query-parallel slicing keeps it skew-proof (R18's fix, layer 2).

#define NNODE 4096
#define CDIM 128
#define TW 132           // partial-table width: 128 features + z at col 128
#define NEG 0.2f
#define CHUNK 32
#define NCHUNK 128       // NNODE / CHUNK

typedef __bf16 bf16x8 __attribute__((ext_vector_type(8)));
typedef float f32x4 __attribute__((ext_vector_type(4)));

__device__ __forceinline__ unsigned short f2b(float f) {
  unsigned int u = __float_as_uint(f);
  u += 0x7fffu + ((u >> 16) & 1u);  // RTNE
  return (unsigned short)(u >> 16);
}

// One kernel: [0,3072) convert x -> bf16; [3072,3168) W1 transpose;
// [3168,3184) W2 transpose; [3184,3216) zero s1/t1; [3216,3224) zero s2/t2.
__global__ __launch_bounds__(256) void prep_kernel(const float* __restrict__ x,
                                                   const float* __restrict__ W1,
                                                   const float* __restrict__ W2,
                                                   unsigned short* __restrict__ xb,
                                                   unsigned short* __restrict__ W1t,
                                                   unsigned short* __restrict__ W2t,
                                                   float* __restrict__ zs1,
                                                   float* __restrict__ zs2) {
  __shared__ float tile[64][65];
  int b = blockIdx.x, t = threadIdx.x;
  if (b < 3072) {  // convert x: 4096*768/4 quads
    int i = b * 256 + t;
    float4 v = ((const float4*)x)[i];
    ushort4 o;
    o.x = f2b(v.x); o.y = f2b(v.y); o.z = f2b(v.z); o.w = f2b(v.w);
    ((ushort4*)xb)[i] = o;
    return;
  }
  if (b >= 3184) {  // zero s/t accumulators
    float4 z = {0.f, 0.f, 0.f, 0.f};
    if (b < 3216) {
      ((float4*)zs1)[(b - 3184) * 256 + t] = z;       // s1+t1: 32768 floats
    } else {
      ((float4*)zs2)[(b - 3216) * 256 + t] = z;       // s2+t2: 8192 floats
    }
    return;
  }
  const float* W; unsigned short* Wt; int K, N, n0, k0;
  if (b < 3072 + 96) {  // W1 [768,512] -> W1t [512,768]
    int b2 = b - 3072; W = W1; Wt = W1t; K = 768; N = 512;
    n0 = (b2 & 7) * 64; k0 = (b2 >> 3) * 64;
  } else {              // W2 [512,128] -> W2t [128,512]
    int b3 = b - 3072 - 96; W = W2; Wt = W2t; K = 512; N = 128;
    n0 = (b3 & 1) * 64; k0 = (b3 >> 1) * 64;
  }
  for (int p = 0; p < 16; p++) {
    int e = p * 256 + t;
    int rr = e >> 6, cc = e & 63;
    tile[rr][cc] = W[(size_t)(k0 + rr) * N + n0 + cc];
  }
  __syncthreads();
  for (int p = 0; p < 16; p++) {
    int e = p * 256 + t;
    int rr = e >> 6, cc = e & 63;  // rr: n-dir, cc: k-dir
    Wt[(size_t)(n0 + rr) * K + k0 + cc] = f2b(tile[cc][rr]);
  }
}

// C[M,N] = A[M,K] x Bt[N,K]^T, both bf16 K-contig. BK=32, 256 thr = 4 waves
// (2x2). Register prefetch of tile k+1 between LDS barrier and MFMA.
// Fused epilogue: s[h][n] / t[h][n] partial dot products from acc registers.
template <int BM, int BN>
__global__ __launch_bounds__(256) void mfma_gemm_bt(const unsigned short* __restrict__ A,
                                                    const unsigned short* __restrict__ Bt,
                                                    float* __restrict__ C,
                                                    int M, int N, int K,
                                                    float* __restrict__ sAcc,
                                                    float* __restrict__ tAcc,
                                                    const float* __restrict__ av_s,
                                                    const float* __restrict__ av_d) {
  __shared__ __align__(16) unsigned short As[BM * 40];
  __shared__ __align__(16) unsigned short Bs[BN * 40];
  constexpr int WM = BM / 2, WN = BN / 2;
  constexpr int FI = WM / 16, FJ = WN / 16;
  constexpr int EA = BM * 32 / 8;
  constexpr int EB = BN * 32 / 8;
  constexpr int NA = (EA + 255) / 256;
  constexpr int NB = (EB + 255) / 256;
  int tid = threadIdx.x;
  int lane = tid & 63, wave = tid >> 6;
  int wm = (wave >> 1) * WM, wn = (wave & 1) * WN;
  int m0 = blockIdx.y * BM, n0 = blockIdx.x * BN;
  int fm = lane & 15, fq = lane >> 4;
  f32x4 acc[FI][FJ] = {};
  uint4 ar[NA], br[NB];
  // preload tile 0
#pragma unroll
  for (int q = 0; q < NA; q++) {
    int e = q * 256 + tid;
    if (e < EA) {
      int r = e >> 2, kk = (e & 3) * 8;
      ar[q] = *(const uint4*)(A + (size_t)(m0 + r) * K + kk);
    }
  }
#pragma unroll
  for (int q = 0; q < NB; q++) {
    int e = q * 256 + tid;
    if (e < EB) {
      int r = e >> 2, kk = (e & 3) * 8;
      br[q] = *(const uint4*)(Bt + (size_t)(n0 + r) * K + kk);
    }
  }
  for (int k0 = 0; k0 < K; k0 += 32) {
    __syncthreads();  // previous iter's ds_reads done before overwrite
#pragma unroll
    for (int q = 0; q < NA; q++) {
      int e = q * 256 + tid;
      if (e < EA) {
        int r = e >> 2, kk = (e & 3) * 8;
        *(uint4*)&As[r * 40 + kk] = ar[q];
      }
    }
#pragma unroll
    for (int q = 0; q < NB; q++) {
      int e = q * 256 + tid;
      if (e < EB) {
        int r = e >> 2, kk = (e & 3) * 8;
        *(uint4*)&Bs[r * 40 + kk] = br[q];
      }
    }
    __syncthreads();
    // prefetch tile k+1 (in flight during ds_read + MFMA below)
    if (k0 + 32 < K) {
#pragma unroll
      for (int q = 0; q < NA; q++) {
        int e = q * 256 + tid;
        if (e < EA) {
          int r = e >> 2, kk = (e & 3) * 8;
          ar[q] = *(const uint4*)(A + (size_t)(m0 + r) * K + k0 + 32 + kk);
        }
      }
#pragma unroll
      for (int q = 0; q < NB; q++) {
        int e = q * 256 + tid;
        if (e < EB) {
          int r = e >> 2, kk = (e & 3) * 8;
          br[q] = *(const uint4*)(Bt + (size_t)(n0 + r) * K + k0 + 32 + kk);
        }
      }
    }
    bf16x8 af[FI], bfr[FJ];
#pragma unroll
    for (int i = 0; i < FI; i++)
      af[i] = *(const bf16x8*)&As[(wm + i * 16 + fm) * 40 + fq * 8];
#pragma unroll
    for (int j = 0; j < FJ; j++)
      bfr[j] = *(const bf16x8*)&Bs[(wn + j * 16 + fm) * 40 + fq * 8];
#pragma unroll
    for (int i = 0; i < FI; i++)
#pragma unroll
      for (int j = 0; j < FJ; j++)
        acc[i][j] = __builtin_amdgcn_mfma_f32_16x16x32_bf16(af[i], bfr[j], acc[i][j], 0, 0, 0);
  }
  // C store
#pragma unroll
  for (int i = 0; i < FI; i++) {
#pragma unroll
    for (int j = 0; j < FJ; j++) {
      int r = m0 + wm + i * 16 + fq * 4;
      int ccol = n0 + wn + j * 16 + fm;
#pragma unroll
      for (int reg = 0; reg < 4; reg++)
        C[(size_t)(r + reg) * N + ccol] = acc[i][j][reg];
    }
  }
  // fused s/t epilogue
  {
    int hh = n0 >> 7;
    float avs[FJ], avd[FJ];
#pragma unroll
    for (int j = 0; j < FJ; j++) {
      int col = n0 + wn + j * 16 + fm;
      avs[j] = av_s[col];
      avd[j] = av_d[col];
    }
#pragma unroll
    for (int i = 0; i < FI; i++) {
#pragma unroll
      for (int reg = 0; reg < 4; reg++) {
        float sv = 0.f, tv = 0.f;
#pragma unroll
        for (int j = 0; j < FJ; j++) {
          sv = fmaf(acc[i][j][reg], avs[j], sv);
          tv = fmaf(acc[i][j][reg], avd[j], tv);
        }
#pragma unroll
        for (int o = 1; o < 16; o <<= 1) {
          sv += __shfl_xor(sv, o, 64);
          tv += __shfl_xor(tv, o, 64);
        }
        if (fm == 0) {
          int row = m0 + wm + i * 16 + fq * 4 + reg;
          atomicAdd(&sAcc[(size_t)hh * NNODE + row], sv);
          atomicAdd(&tAcc[(size_t)hh * NNODE + row], tv);
        }
      }
    }
  }
}

// One-kernel rank sort + query split precompute. All 4096 keys in LDS.
// ALSO counts lo[n] = #{j : s_j < -t_n} (strict <, == lower_bound).
__global__ __launch_bounds__(256) void rank_sort_kernel(const float* __restrict__ s,
                                                        const float* __restrict__ t,
                                                        float* __restrict__ ss,
                                                        int* __restrict__ si,
                                                        int* __restrict__ qlo) {
  __shared__ __align__(16) float keys[NNODE];
  __shared__ int pc[8][32], qc[8][32];
  int hh = blockIdx.y, tid = threadIdx.x;
  const float* sp = s + (size_t)hh * NNODE;
  for (int k = tid; k < NNODE / 4; k += 256)
    ((float4*)keys)[k] = ((const float4*)sp)[k];
  __syncthreads();
  int slot = tid & 31, part = tid >> 5;
  int node = blockIdx.x * 32 + slot;
  float mk = keys[node];
  float qk = -t[(size_t)hh * NNODE + node];
  int cnt = 0, cq = 0;
  int j0 = part * 512;
#pragma unroll 4
  for (int j = j0; j < j0 + 512; j += 4) {
    float4 kv = *(const float4*)&keys[j];
    cnt += (kv.x < mk) || (kv.x == mk && (j + 0) < node);
    cnt += (kv.y < mk) || (kv.y == mk && (j + 1) < node);
    cnt += (kv.z < mk) || (kv.z == mk && (j + 2) < node);
    cnt += (kv.w < mk) || (kv.w == mk && (j + 3) < node);
    cq += (kv.x < qk) + (kv.y < qk) + (kv.z < qk) + (kv.w < qk);
  }
  pc[part][slot] = cnt;
  qc[part][slot] = cq;
  __syncthreads();
  if (tid < 32) {
    int rank = 0;
#pragma unroll
    for (int p = 0; p < 8; p++) rank += pc[p][tid];
    int n2 = blockIdx.x * 32 + tid;
    ss[(size_t)hh * NNODE + rank] = keys[n2];
    si[(size_t)hh * NNODE + rank] = n2;
  } else if (tid < 64) {
    int sl = tid - 32;
    int lo = 0;
#pragma unroll
    for (int p = 0; p < 8; p++) lo += qc[p][sl];
    qlo[(size_t)hh * NNODE + blockIdx.x * 32 + sl] = lo;
  }
}

// Pass A: per-chunk partial sums of e^{s}*h (P) and e^{0.2s}*h (M); z at 128.
__global__ __launch_bounds__(128) void passA_kernel(const float* __restrict__ h,
                                                    const float* __restrict__ ss,
                                                    const int* __restrict__ si,
                                                    float* __restrict__ partP,
                                                    float* __restrict__ partM, int H) {
  __shared__ float eP[CHUNK], eM[CHUNK];
  __shared__ int ids[CHUNK];
  int b = blockIdx.x, hh = b / NCHUNK, ci = b % NCHUNK;
  int c = threadIdx.x;
  int HC = H * CDIM;
  int base = ci * CHUNK;
  if (c < CHUNK) {
    float sv = ss[(size_t)hh * NNODE + base + c];
    ids[c] = si[(size_t)hh * NNODE + base + c];
    eP[c] = expf(sv);
    eM[c] = expf(NEG * sv);
  }
  __syncthreads();
  float sp = 0.f, sm = 0.f;
  for (int kb = 0; kb < CHUNK; kb += 8) {
    float v[8];
#pragma unroll
    for (int j = 0; j < 8; j++)
      v[j] = h[(size_t)ids[kb + j] * HC + hh * CDIM + c];
#pragma unroll
    for (int j = 0; j < 8; j++) {
      sp = fmaf(eP[kb + j], v[j], sp);
      sm = fmaf(eM[kb + j], v[j], sm);
    }
  }
  size_t o = ((size_t)hh * NCHUNK + ci) * TW;
  partP[o + c] = sp;
  partM[o + c] = sm;
  if (c == 0) {
    float zp = 0.f, zm = 0.f;
#pragma unroll
    for (int k = 0; k < CHUNK; k++) { zp += eP[k]; zm += eM[k]; }
    partP[o + 128] = zp;
    partM[o + 128] = zm;
  }
}

// Pass B, grid (3, H): dir 0 = exclusive prefix of partM; dir 1 = exclusive
// suffix of partP; dir 2 = bucket queries by split chunk (counting scatter).
__global__ __launch_bounds__(192) void passB_kernel(const float* __restrict__ partP,
                                                    const float* __restrict__ partM,
                                                    float* __restrict__ sufP,
                                                    float* __restrict__ prefM,
                                                    const int* __restrict__ qlo,
                                                    int* __restrict__ qbuf) {
  __shared__ int hist[NCHUNK];
  __shared__ int offs[NCHUNK];
  int hh = blockIdx.y, dir = blockIdx.x;
  int c = threadIdx.x;
  if (dir == 2) {  // bucket: counting sort of queries by lo>>5
    const int* ql = qlo + (size_t)hh * NNODE;
    for (int i = c; i < NCHUNK; i += 192) hist[i] = 0;
    __syncthreads();
    for (int i = c; i < NNODE; i += 192) {
      int bin = ql[i] >> 5; bin = bin > NCHUNK - 1 ? NCHUNK - 1 : bin;
      atomicAdd(&hist[bin], 1);
    }
    __syncthreads();
    if (c == 0) {
      int run = 0;
      for (int k = 0; k < NCHUNK; k++) { offs[k] = run; run += hist[k]; }
    }
    __syncthreads();
    for (int i = c; i < NCHUNK; i += 192) hist[i] = offs[i];
    __syncthreads();
    for (int i = c; i < NNODE; i += 192) {
      int bin = ql[i] >> 5; bin = bin > NCHUNK - 1 ? NCHUNK - 1 : bin;
      int pos = atomicAdd(&hist[bin], 1);
      qbuf[(size_t)hh * NNODE + pos] = i;
    }
    return;
  }
  if (c > 128) return;  // 129 cols: 128 features + z
  size_t base = (size_t)hh * NCHUNK * TW;
  if (dir == 0) {  // forward exclusive prefix of partM
    float run = 0.f;
    for (int g0 = 0; g0 < NCHUNK; g0 += 8) {
      float v[8];
#pragma unroll
      for (int j = 0; j < 8; j++) v[j] = partM[base + (size_t)(g0 + j) * TW + c];
#pragma unroll
      for (int j = 0; j < 8; j++) {
        prefM[base + (size_t)(g0 + j) * TW + c] = run;
        run += v[j];
      }
    }
  } else {  // backward exclusive suffix of partP
    float run = 0.f;
    for (int g0 = NCHUNK - 8; g0 >= 0; g0 -= 8) {
      float v[8];
#pragma unroll
      for (int j = 7; j >= 0; j--) v[j] = partP[base + (size_t)(g0 + j) * TW + c];
#pragma unroll
      for (int j = 7; j >= 0; j--) {
        sufP[base + (size_t)(g0 + j) * TW + c] = run;
        run += v[j];
      }
    }
  }
}

// Pass D v3 (query-parallel + LDS-resident tables): block owns 32
// consecutive bucketed queries. Per chunk-run: stage 32 e*h rows, build
// prefix table (half 0, eM asc) and suffix table (half 1, eP desc) ONCE
// in LDS -- same accumulation order as the global table scan -- then each
// query reads 2 LDS rows + passB carries, bias, ELU.
template <typename OUT>
__global__ __launch_bounds__(256) void passD_kernel(const float* __restrict__ h,
                                                    const float* __restrict__ ss,
                                                    const int* __restrict__ si,
                                                    const int* __restrict__ qlo,
                                                    const int* __restrict__ qbuf,
                                                    const float* __restrict__ fP,
                                                    const float* __restrict__ fM,
                                                    const float* __restrict__ tt,
                                                    const float* __restrict__ bias,
                                                    OUT* __restrict__ out, int H) {
  __shared__ float hrow[CHUNK][CDIM];        // 16.0 KB
  __shared__ float PPl[CHUNK + 1][CDIM];     // 16.5 KB (exclusive prefix, k=0..32)
  __shared__ float SSl[CHUNK + 1][CDIM];     // 16.5 KB (inclusive suffix, k=0..32)
  __shared__ float zPP[CHUNK + 1], zSS[CHUNK + 1];
  __shared__ float eP[CHUNK], eM[CHUNK];
  __shared__ int ids[CHUNK];
  __shared__ int qn[32], qL[32];
  __shared__ float qt[32];
  int b = blockIdx.x;
  int hh = b >> 7, qb = (b & 127) * 32;  // grid = H * 128
  int tid = threadIdx.x;
  int c = tid & 127, half = tid >> 7;
  int HC = H * CDIM;
  // prestage query metadata (one parallel scattered round)
  if (tid < 32) {
    int n = qbuf[(size_t)hh * NNODE + qb + tid];
    qn[tid] = n;
    qL[tid] = qlo[(size_t)hh * NNODE + n];
    qt[tid] = tt[(size_t)hh * NNODE + n];
  }
  __syncthreads();
  float bv = bias[hh * CDIM + c];
  int it = 0;
  while (it < 32) {
    int lo0 = qL[it];
    int ci = lo0 >> 5; if (ci > NCHUNK - 1) ci = NCHUNK - 1;
    int ie = it + 1;
    while (ie < 32) {
      int cj = qL[ie] >> 5; if (cj > NCHUNK - 1) cj = NCHUNK - 1;
      if (cj != ci) break;
      ie++;
    }
    int base = ci * CHUNK;
    __syncthreads();  // protect previous run's LDS reads
    if (tid < CHUNK) {
      float sv = ss[(size_t)hh * NNODE + base + tid];
      ids[tid] = si[(size_t)hh * NNODE + base + tid];
      eP[tid] = expf(sv);
      eM[tid] = expf(NEG * sv);
    }
    __syncthreads();
    // gather chunk rows (half 0: rows 0..15, half 1: rows 16..31)
    for (int kb = half * 16; kb < half * 16 + 16; kb += 8) {
      float v[8];
#pragma unroll
      for (int j = 0; j < 8; j++)
        v[j] = h[(size_t)ids[kb + j] * HC + hh * CDIM + c];
#pragma unroll
      for (int j = 0; j < 8; j++) hrow[kb + j][c] = v[j];
    }
    __syncthreads();
    // build tables once: half 0 = eM exclusive prefix (ascending),
    // half 1 = eP inclusive suffix (descending). Same order as old scans.
    if (half == 0) {
      float run = 0.f, runz = 0.f;
#pragma unroll 8
      for (int k = 0; k < CHUNK; k++) {
        PPl[k][c] = run;
        if (c == 0) zPP[k] = runz;
        run = fmaf(eM[k], hrow[k][c], run);
        runz += eM[k];
      }
      PPl[CHUNK][c] = run;
      if (c == 0) zPP[CHUNK] = runz;
    } else {
      float run = 0.f, runz = 0.f;
      SSl[CHUNK][c] = 0.f;
      if (c == 0) zSS[CHUNK] = 0.f;
#pragma unroll 8
      for (int k = CHUNK - 1; k >= 0; k--) {
        run = fmaf(eP[k], hrow[k][c], run);
        runz += eP[k];
        SSl[k][c] = run;
        if (c == 0) zSS[k] = runz;
      }
    }
    __syncthreads();
    size_t co = ((size_t)hh * NCHUNK + ci) * TW;
    float rfP = fP[co + c], rfM = fM[co + c];
    float rfPz = fP[co + 128], rfMz = fM[co + 128];
    for (int q = it + half; q < ie; q += 2) {
      int n = qn[q];
      float tv = qt[q];
      int loc = qL[q] - base;  // in [0, 32]
      float wp = expf(tv), wm = expf(NEG * tv);
      float num = wp * (SSl[loc][c] + rfP) + wm * (PPl[loc][c] + rfM);
      float Z = wp * (zSS[loc] + rfPz) + wm * (zPP[loc] + rfMz);
      float ov = num / Z + bv;
      float r = (ov > 0.f) ? ov : (expf(ov) - 1.f);
      if constexpr (sizeof(OUT) == 2)
        out[(size_t)n * HC + hh * CDIM + c] = f2b(r);
      else
        out[(size_t)n * HC + hh * CDIM + c] = r;
    }
    it = ie;
  }
}

// Coalesced column partial sums: block b sums rows [b*64, b*64+64) into
// part[b][128]. float4 loads, LDS tree over row-groups. No atomics.
__global__ __launch_bounds__(256) void mean_part_kernel(const float* __restrict__ x,
                                                        float* __restrict__ part) {
  __shared__ float4 red[256];
  int b = blockIdx.x, tid = threadIdx.x;
  int q = tid & 31, r0 = tid >> 5;  // q: col quad (4 cols), r0: row group
  const float4* xp = (const float4*)x;
  float4 s = {0.f, 0.f, 0.f, 0.f};
  int base = b * 64;
  for (int r = r0; r < 64; r += 8) {
    float4 v = xp[(size_t)(base + r) * 32 + q];
    s.x += v.x; s.y += v.y; s.z += v.z; s.w += v.w;
  }
  red[tid] = s; __syncthreads();
  for (int off = 4; off > 0; off >>= 1) {
    if (r0 < off) {
      float4 o = red[tid + off * 32];
      red[tid].x += o.x; red[tid].y += o.y; red[tid].z += o.z; red[tid].w += o.w;
    }
    __syncthreads();
  }
  if (tid < 32) ((float4*)part)[b * 32 + tid] = red[tid];
}

// Reduce the 64x128 partials (redundantly per block, trivial) then GEMV.
__global__ __launch_bounds__(256) void fc_kernel(const float* __restrict__ part,
                                                 const float* __restrict__ fcW,
                                                 const float* __restrict__ fcb,
                                                 float* __restrict__ out) {
  __shared__ float tmp[256];
  __shared__ float m[CDIM];
  int tid = threadIdx.x;
  int c = tid & 127, half = tid >> 7;
  float a = 0.f;
  for (int g = half; g < 64; g += 2) a += part[g * CDIM + c];
  tmp[tid] = a; __syncthreads();
  if (tid < 128) m[tid] = (tmp[tid] + tmp[tid + 128]) * (1.f / NNODE);
  __syncthreads();
  int d = blockIdx.x * 256 + tid;  // 768 total
  float acc = fcb[d];
#pragma unroll 4
  for (int c2 = 0; c2 < CDIM; c2++) acc = fmaf(m[c2], fcW[c2 * 768 + d], acc);
  out[d] = acc;
}

extern "C" void kernel_launch(void* const* d_in, const int* in_sizes, int n_in,
                              void* d_out, int out_size, void* d_ws, size_t ws_size,
                              hipStream_t stream) {
  const float* x   = (const float*)d_in[0];
  const float* W1  = (const float*)d_in[1];
  const float* as1 = (const float*)d_in[2];
  const float* ad1 = (const float*)d_in[3];
  const float* b1  = (const float*)d_in[4];
  const float* W2  = (const float*)d_in[5];
  const float* as2 = (const float*)d_in[6];
  const float* ad2 = (const float*)d_in[7];
  const float* b2  = (const float*)d_in[8];
  const float* fcW = (const float*)d_in[9];
  const float* fcb = (const float*)d_in[10];

  float* ws = (float*)d_ws;
  size_t off = 0;
  auto alloc = [&](size_t nfloats) { float* p = ws + off; off += nfloats; return p; };

  float* h1  = alloc((size_t)NNODE * 512);
  float* x2f = alloc((size_t)NNODE * 256 + 64 + 16384);  // x2b bf16 + W2t bf16
  float* h2  = alloc((size_t)NNODE * 128);
  float* x3  = alloc((size_t)NNODE * 128);
  float* xbf = alloc((size_t)NNODE * 384);   // x bf16 4096x768
  float* w1f = alloc((size_t)512 * 384);     // W1t bf16 512x768
  float* s1  = alloc((size_t)4 * NNODE);
  float* t1  = alloc((size_t)4 * NNODE);
  float* sS1 = alloc((size_t)4 * NNODE);
  int*   sI1 = (int*)alloc((size_t)4 * NNODE);
  int*   qL1 = (int*)alloc((size_t)4 * NNODE);
  int*   qB1 = (int*)alloc((size_t)4 * NNODE);
  float* pP1 = alloc((size_t)4 * NCHUNK * TW);
  float* pM1 = alloc((size_t)4 * NCHUNK * TW);
  float* fP1 = alloc((size_t)4 * NCHUNK * TW);   // chunk suffix of P
  float* fM1 = alloc((size_t)4 * NCHUNK * TW);   // chunk prefix of M
  float* s2  = alloc(NNODE);
  float* t2  = alloc(NNODE);
  float* sS2 = alloc(NNODE);
  int*   sI2 = (int*)alloc(NNODE);
  int*   qL2 = (int*)alloc(NNODE);
  int*   qB2 = (int*)alloc(NNODE);
  float* pP2 = alloc((size_t)NCHUNK * TW);
  float* pM2 = alloc((size_t)NCHUNK * TW);
  float* fP2 = alloc((size_t)NCHUNK * TW);
  float* fM2 = alloc((size_t)NCHUNK * TW);
  float* mpart = alloc((size_t)64 * CDIM);  // mean partial sums

  unsigned short* xb  = (unsigned short*)xbf;
  unsigned short* W1t = (unsigned short*)w1f;
  unsigned short* x2b = (unsigned short*)x2f;                       // 4096x512 bf16
  unsigned short* W2t = (unsigned short*)(x2f + NNODE * 256 + 64);  // 128x512 bf16

  // Prep: convert x + transpose/cast W1, W2 + zero s/t accumulators
  prep_kernel<<<3224, 256, 0, stream>>>(x, W1, W2, xb, W1t, W2t, s1, s2);
  // Layer 1 (fused s/t epilogue)
  mfma_gemm_bt<64, 64><<<dim3(512 / 64, NNODE / 64), 256, 0, stream>>>(
      xb, W1t, h1, NNODE, 512, 768, s1, t1, as1, ad1);
  rank_sort_kernel<<<dim3(NNODE / 32, 4), 256, 0, stream>>>(s1, t1, sS1, sI1, qL1);
  passA_kernel<<<4 * NCHUNK, 128, 0, stream>>>(h1, sS1, sI1, pP1, pM1, 4);
  passB_kernel<<<dim3(3, 4), 192, 0, stream>>>(pP1, pM1, fP1, fM1, qL1, qB1);
  passD_kernel<unsigned short><<<4 * 128, 256, 0, stream>>>(
      h1, sS1, sI1, qL1, qB1, fP1, fM1, t1, b1, x2b, 4);
  // Layer 2 (fused s/t epilogue)
  mfma_gemm_bt<32, 64><<<dim3(128 / 64, NNODE / 32), 256, 0, stream>>>(
      x2b, W2t, h2, NNODE, 128, 512, s2, t2, as2, ad2);
  rank_sort_kernel<<<dim3(NNODE / 32, 1), 256, 0, stream>>>(s2, t2, sS2, sI2, qL2);
  passA_kernel<<<NCHUNK, 128, 0, stream>>>(h2, sS2, sI2, pP2, pM2, 1);
  passB_kernel<<<dim3(3, 1), 192, 0, stream>>>(pP2, pM2, fP2, fM2, qL2, qB2);
  passD_kernel<float><<<128, 256, 0, stream>>>(
      h2, sS2, sI2, qL2, qB2, fP2, fM2, t2, b2, x3, 1);
  // Readout: coalesced mean partials + fc
  mean_part_kernel<<<64, 256, 0, stream>>>(x3, mpart);
  fc_kernel<<<3, 256, 0, stream>>>(mpart, fcW, fcb, (float*)d_out);
}

// Round 9
// 234.714 us; speedup vs baseline: 8.1262x; 1.0427x over previous
//
#include <hip/hip_runtime.h>
#include <hip/hip_bf16.h>

// FacePartGAT: dense-graph GATConv x2 + mean + fc on MI355X. ALL I/O fp32.
// e[i,j] = leaky_relu(t_i + s_j) => softmax aggregation factorizes after
// sorting sources by s_j (prefix/suffix tables + split-point lookup). Exact.
// Round 20: revert to R16 structure (best: 204us; R17-19's table-free passD
// variants all regressed -- global tables are L2-resident, the round-trip
// was already cheap). Two surgical cuts on top:
//  - attend2 fuses the mean: atomicAdd ELU rows into 64x128 mpart bins
//    (32 blocks/bin, prep zeroes mpart). Drops mean_part dispatch + x3.
//  - GEMM BK 32->64 (stride-72 LDS): halves barrier count, deeper prefetch.

#define NNODE 4096
#define CDIM 128
#define TW 132           // table width: 128 features + z at col 128
#define NEG 0.2f
#define CHUNK 32
#define NCHUNK 128       // NNODE / CHUNK

typedef __bf16 bf16x8 __attribute__((ext_vector_type(8)));
typedef float f32x4 __attribute__((ext_vector_type(4)));

__device__ __forceinline__ unsigned short f2b(float f) {
  unsigned int u = __float_as_uint(f);
  u += 0x7fffu + ((u >> 16) & 1u);  // RTNE
  return (unsigned short)(u >> 16);
}

// One kernel: [0,3072) convert x -> bf16; [3072,3168) W1 transpose;
// [3168,3184) W2 transpose; [3184,3216) zero s1/t1; [3216,3224) zero s2/t2;
// [3224,3232) zero mpart.
__global__ __launch_bounds__(256) void prep_kernel(const float* __restrict__ x,
                                                   const float* __restrict__ W1,
                                                   const float* __restrict__ W2,
                                                   unsigned short* __restrict__ xb,
                                                   unsigned short* __restrict__ W1t,
                                                   unsigned short* __restrict__ W2t,
                                                   float* __restrict__ zs1,
                                                   float* __restrict__ zs2,
                                                   float* __restrict__ zmp) {
  __shared__ float tile[64][65];
  int b = blockIdx.x, t = threadIdx.x;
  if (b < 3072) {  // convert x: 4096*768/4 quads
    int i = b * 256 + t;
    float4 v = ((const float4*)x)[i];
    ushort4 o;
    o.x = f2b(v.x); o.y = f2b(v.y); o.z = f2b(v.z); o.w = f2b(v.w);
    ((ushort4*)xb)[i] = o;
    return;
  }
  if (b >= 3184) {  // zero regions
    float4 z = {0.f, 0.f, 0.f, 0.f};
    if (b < 3216) {
      ((float4*)zs1)[(b - 3184) * 256 + t] = z;       // s1+t1: 32768 floats
    } else if (b < 3224) {
      ((float4*)zs2)[(b - 3216) * 256 + t] = z;       // s2+t2: 8192 floats
    } else {
      ((float4*)zmp)[(b - 3224) * 256 + t] = z;       // mpart: 8192 floats
    }
    return;
  }
  const float* W; unsigned short* Wt; int K, N, n0, k0;
  if (b < 3072 + 96) {  // W1 [768,512] -> W1t [512,768]
    int b2 = b - 3072; W = W1; Wt = W1t; K = 768; N = 512;
    n0 = (b2 & 7) * 64; k0 = (b2 >> 3) * 64;
  } else {              // W2 [512,128] -> W2t [128,512]
    int b3 = b - 3072 - 96; W = W2; Wt = W2t; K = 512; N = 128;
    n0 = (b3 & 1) * 64; k0 = (b3 >> 1) * 64;
  }
  for (int p = 0; p < 16; p++) {
    int e = p * 256 + t;
    int rr = e >> 6, cc = e & 63;
    tile[rr][cc] = W[(size_t)(k0 + rr) * N + n0 + cc];
  }
  __syncthreads();
  for (int p = 0; p < 16; p++) {
    int e = p * 256 + t;
    int rr = e >> 6, cc = e & 63;  // rr: n-dir, cc: k-dir
    Wt[(size_t)(n0 + rr) * K + k0 + cc] = f2b(tile[cc][rr]);
  }
}

// C[M,N] = A[M,K] x Bt[N,K]^T, both bf16 K-contig. BK=64 (2 MFMA k-steps
// per stage, half the barriers of BK=32), 256 thr = 4 waves (2x2), stride-72
// LDS rows (144B, 16B-aligned, bank-spread). Register prefetch of tile k+1.
// Fused epilogue: s/t row-dots from acc registers (shfl reduce + atomicAdd).
template <int BM, int BN>
__global__ __launch_bounds__(256) void mfma_gemm_bt(const unsigned short* __restrict__ A,
                                                    const unsigned short* __restrict__ Bt,
                                                    float* __restrict__ C,
                                                    int M, int N, int K,
                                                    float* __restrict__ sAcc,
                                                    float* __restrict__ tAcc,
                                                    const float* __restrict__ av_s,
                                                    const float* __restrict__ av_d) {
  __shared__ __align__(16) unsigned short As[BM * 72];
  __shared__ __align__(16) unsigned short Bs[BN * 72];
  constexpr int WM = BM / 2, WN = BN / 2;
  constexpr int FI = WM / 16, FJ = WN / 16;
  constexpr int EA = BM * 8;   // uint4 quads per A tile (BK=64 -> 8 quads/row)
  constexpr int EB = BN * 8;
  constexpr int NA = (EA + 255) / 256;
  constexpr int NB = (EB + 255) / 256;
  int tid = threadIdx.x;
  int lane = tid & 63, wave = tid >> 6;
  int wm = (wave >> 1) * WM, wn = (wave & 1) * WN;
  int m0 = blockIdx.y * BM, n0 = blockIdx.x * BN;
  int fm = lane & 15, fq = lane >> 4;
  f32x4 acc[FI][FJ] = {};
  uint4 ar[NA], br[NB];
  // preload tile 0
#pragma unroll
  for (int q = 0; q < NA; q++) {
    int e = q * 256 + tid;
    if (e < EA) {
      int r = e >> 3, kk = (e & 7) * 8;
      ar[q] = *(const uint4*)(A + (size_t)(m0 + r) * K + kk);
    }
  }
#pragma unroll
  for (int q = 0; q < NB; q++) {
    int e = q * 256 + tid;
    if (e < EB) {
      int r = e >> 3, kk = (e & 7) * 8;
      br[q] = *(const uint4*)(Bt + (size_t)(n0 + r) * K + kk);
    }
  }
  for (int k0 = 0; k0 < K; k0 += 64) {
    __syncthreads();  // previous iter's ds_reads done before overwrite
#pragma unroll
    for (int q = 0; q < NA; q++) {
      int e = q * 256 + tid;
      if (e < EA) {
        int r = e >> 3, kk = (e & 7) * 8;
        *(uint4*)&As[r * 72 + kk] = ar[q];
      }
    }
#pragma unroll
    for (int q = 0; q < NB; q++) {
      int e = q * 256 + tid;
      if (e < EB) {
        int r = e >> 3, kk = (e & 7) * 8;
        *(uint4*)&Bs[r * 72 + kk] = br[q];
      }
    }
    __syncthreads();
    // prefetch tile k+1 (in flight during ds_read + MFMA below)
    if (k0 + 64 < K) {
#pragma unroll
      for (int q = 0; q < NA; q++) {
        int e = q * 256 + tid;
        if (e < EA) {
          int r = e >> 3, kk = (e & 7) * 8;
          ar[q] = *(const uint4*)(A + (size_t)(m0 + r) * K + k0 + 64 + kk);
        }
      }
#pragma unroll
      for (int q = 0; q < NB; q++) {
        int e = q * 256 + tid;
        if (e < EB) {
          int r = e >> 3, kk = (e & 7) * 8;
          br[q] = *(const uint4*)(Bt + (size_t)(n0 + r) * K + k0 + 64 + kk);
        }
      }
    }
#pragma unroll
    for (int kk2 = 0; kk2 < 2; kk2++) {
      bf16x8 af[FI], bfr[FJ];
#pragma unroll
      for (int i = 0; i < FI; i++)
        af[i] = *(const bf16x8*)&As[(wm + i * 16 + fm) * 72 + kk2 * 32 + fq * 8];
#pragma unroll
      for (int j = 0; j < FJ; j++)
        bfr[j] = *(const bf16x8*)&Bs[(wn + j * 16 + fm) * 72 + kk2 * 32 + fq * 8];
#pragma unroll
      for (int i = 0; i < FI; i++)
#pragma unroll
        for (int j = 0; j < FJ; j++)
          acc[i][j] = __builtin_amdgcn_mfma_f32_16x16x32_bf16(af[i], bfr[j], acc[i][j], 0, 0, 0);
    }
  }
  // C store
#pragma unroll
  for (int i = 0; i < FI; i++) {
#pragma unroll
    for (int j = 0; j < FJ; j++) {
      int r = m0 + wm + i * 16 + fq * 4;
      int ccol = n0 + wn + j * 16 + fm;
#pragma unroll
      for (int reg = 0; reg < 4; reg++)
        C[(size_t)(r + reg) * N + ccol] = acc[i][j][reg];
    }
  }
  // fused s/t epilogue
  {
    int hh = n0 >> 7;
    float avs[FJ], avd[FJ];
#pragma unroll
    for (int j = 0; j < FJ; j++) {
      int col = n0 + wn + j * 16 + fm;
      avs[j] = av_s[col];
      avd[j] = av_d[col];
    }
#pragma unroll
    for (int i = 0; i < FI; i++) {
#pragma unroll
      for (int reg = 0; reg < 4; reg++) {
        float sv = 0.f, tv = 0.f;
#pragma unroll
        for (int j = 0; j < FJ; j++) {
          sv = fmaf(acc[i][j][reg], avs[j], sv);
          tv = fmaf(acc[i][j][reg], avd[j], tv);
        }
#pragma unroll
        for (int o = 1; o < 16; o <<= 1) {
          sv += __shfl_xor(sv, o, 64);
          tv += __shfl_xor(tv, o, 64);
        }
        if (fm == 0) {
          int row = m0 + wm + i * 16 + fq * 4 + reg;
          atomicAdd(&sAcc[(size_t)hh * NNODE + row], sv);
          atomicAdd(&tAcc[(size_t)hh * NNODE + row], tv);
        }
      }
    }
  }
}

// One-kernel rank sort + query split precompute. All 4096 keys in LDS
// (16 KB). Block = 32 nodes x 8 scan-parts of 512 keys; partial counts
// combined in LDS; direct scatter of (key, idx) to sorted position.
// ALSO counts lo[n] = #{j : s_j < -t_n} (strict <, == lower_bound).
__global__ __launch_bounds__(256) void rank_sort_kernel(const float* __restrict__ s,
                                                        const float* __restrict__ t,
                                                        float* __restrict__ ss,
                                                        int* __restrict__ si,
                                                        int* __restrict__ qlo) {
  __shared__ __align__(16) float keys[NNODE];
  __shared__ int pc[8][32], qc[8][32];
  int hh = blockIdx.y, tid = threadIdx.x;
  const float* sp = s + (size_t)hh * NNODE;
  for (int k = tid; k < NNODE / 4; k += 256)
    ((float4*)keys)[k] = ((const float4*)sp)[k];
  __syncthreads();
  int slot = tid & 31, part = tid >> 5;
  int node = blockIdx.x * 32 + slot;
  float mk = keys[node];
  float qk = -t[(size_t)hh * NNODE + node];
  int cnt = 0, cq = 0;
  int j0 = part * 512;
#pragma unroll 4
  for (int j = j0; j < j0 + 512; j += 4) {
    float4 kv = *(const float4*)&keys[j];
    cnt += (kv.x < mk) || (kv.x == mk && (j + 0) < node);
    cnt += (kv.y < mk) || (kv.y == mk && (j + 1) < node);
    cnt += (kv.z < mk) || (kv.z == mk && (j + 2) < node);
    cnt += (kv.w < mk) || (kv.w == mk && (j + 3) < node);
    cq += (kv.x < qk) + (kv.y < qk) + (kv.z < qk) + (kv.w < qk);
  }
  pc[part][slot] = cnt;
  qc[part][slot] = cq;
  __syncthreads();
  if (tid < 32) {
    int rank = 0;
#pragma unroll
    for (int p = 0; p < 8; p++) rank += pc[p][tid];
    int n2 = blockIdx.x * 32 + tid;
    ss[(size_t)hh * NNODE + rank] = keys[n2];
    si[(size_t)hh * NNODE + rank] = n2;
  } else if (tid < 64) {
    int sl = tid - 32;
    int lo = 0;
#pragma unroll
    for (int p = 0; p < 8; p++) lo += qc[p][sl];
    qlo[(size_t)hh * NNODE + blockIdx.x * 32 + sl] = lo;
  }
}

// Fused passA+passC: gather h rows ONCE, dual LOCAL scans (tables start at
// zero carry; attend adds chunk carries). The chunk partial sums for passB
// fall out as the scans' final running values. z at col 128.
__global__ __launch_bounds__(128) void passAC_kernel(const float* __restrict__ h,
                                                     const float* __restrict__ ss,
                                                     const int* __restrict__ si,
                                                     float* __restrict__ partP,
                                                     float* __restrict__ partM,
                                                     float* __restrict__ SS,
                                                     float* __restrict__ PP, int H) {
  __shared__ float hrow[CHUNK][CDIM];  // 16 KB
  __shared__ float eP[CHUNK], eM[CHUNK];
  __shared__ int ids[CHUNK];
  int b = blockIdx.x, hh = b / NCHUNK, ci = b % NCHUNK;
  int c = threadIdx.x;
  int HC = H * CDIM;
  int base = ci * CHUNK;
  size_t hb = (size_t)hh * (NNODE + 1);
  if (c < CHUNK) {
    float sv = ss[(size_t)hh * NNODE + base + c];
    ids[c] = si[(size_t)hh * NNODE + base + c];
    eP[c] = expf(sv);
    eM[c] = expf(NEG * sv);
  }
  __syncthreads();
  // gather h rows once into LDS (batched, per-thread column)
  for (int kb = 0; kb < CHUNK; kb += 8) {
    float v[8];
#pragma unroll
    for (int j = 0; j < 8; j++)
      v[j] = h[(size_t)ids[kb + j] * HC + hh * CDIM + c];
#pragma unroll
    for (int j = 0; j < 8; j++) hrow[kb + j][c] = v[j];
  }
  // M forward local prefix (exclusive); final run == chunk partial for passB
  float runm = 0.f, runzm = 0.f;
#pragma unroll 8
  for (int k = 0; k < CHUNK; k++) {
    size_t row = (hb + base + k) * TW;
    PP[row + c] = runm;
    if (c == 0) PP[row + 128] = runzm;
    runm = fmaf(eM[k], hrow[k][c], runm);
    runzm += eM[k];
  }
  size_t o = ((size_t)hh * NCHUNK + ci) * TW;
  partM[o + c] = runm;
  if (c == 0) partM[o + 128] = runzm;
  if (ci == NCHUNK - 1) {
    size_t row = (hb + NNODE) * TW;
    PP[row + c] = runm;
    if (c == 0) PP[row + 128] = runzm;
  }
  // P backward local suffix (inclusive); final run == chunk partial
  float runp = 0.f, runzp = 0.f;
#pragma unroll 8
  for (int k = CHUNK - 1; k >= 0; k--) {
    runp = fmaf(eP[k], hrow[k][c], runp);
    runzp += eP[k];
    size_t row = (hb + base + k) * TW;
    SS[row + c] = runp;
    if (c == 0) SS[row + 128] = runzp;
  }
  partP[o + c] = runp;
  if (c == 0) partP[o + 128] = runzp;
  if (ci == NCHUNK - 1) {
    size_t row = (hb + NNODE) * TW;
    SS[row + c] = 0.f;
    if (c == 0) SS[row + 128] = 0.f;
  }
}

// Pass B: per-head exclusive prefix scan of partM (forward) and exclusive
// suffix scan of partP (backward) over the NCHUNK chunk partials, incl. z.
__global__ __launch_bounds__(192) void passB_kernel(const float* __restrict__ partP,
                                                    const float* __restrict__ partM,
                                                    float* __restrict__ sufP,
                                                    float* __restrict__ prefM) {
  int hh = blockIdx.y, dir = blockIdx.x;
  int c = threadIdx.x;
  if (c > 128) return;  // 129 cols: 128 features + z
  size_t base = (size_t)hh * NCHUNK * TW;
  if (dir == 0) {  // forward exclusive prefix of partM
    float run = 0.f;
    for (int g0 = 0; g0 < NCHUNK; g0 += 8) {
      float v[8];
#pragma unroll
      for (int j = 0; j < 8; j++) v[j] = partM[base + (size_t)(g0 + j) * TW + c];
#pragma unroll
      for (int j = 0; j < 8; j++) {
        prefM[base + (size_t)(g0 + j) * TW + c] = run;
        run += v[j];
      }
    }
  } else {  // backward exclusive suffix of partP
    float run = 0.f;
    for (int g0 = NCHUNK - 8; g0 >= 0; g0 -= 8) {
      float v[8];
#pragma unroll
      for (int j = 7; j >= 0; j--) v[j] = partP[base + (size_t)(g0 + j) * TW + c];
#pragma unroll
      for (int j = 7; j >= 0; j--) {
        sufP[base + (size_t)(g0 + j) * TW + c] = run;
        run += v[j];
      }
    }
  }
}

// Per (dest, head): local table row at precomputed split + chunk carry
// (fP/fM, L2-resident), +bias, ELU. 2 queries per 256-thread block.
// MEANOUT: instead of storing rows, atomicAdd into 64x128 mean bins
// (bin = blockIdx & 63; 32 blocks/bin -> negligible contention).
template <typename OUT, bool MEANOUT>
__global__ __launch_bounds__(256) void attend_kernel(const float* __restrict__ SS,
                                                     const float* __restrict__ PP,
                                                     const float* __restrict__ fP,
                                                     const float* __restrict__ fM,
                                                     const int* __restrict__ qlo,
                                                     const float* __restrict__ tt,
                                                     const float* __restrict__ bias,
                                                     OUT* __restrict__ out,
                                                     float* __restrict__ mpart, int H) {
  int half = threadIdx.x >> 7, c = threadIdx.x & 127;
  int o = blockIdx.x * 2 + half;
  int n = o / H, hh = o % H;
  float tv = tt[(size_t)hh * NNODE + n];
  int lo = qlo[(size_t)hh * NNODE + n];
  int ci = lo >> 5;                      // CHUNK = 32
  if (ci > NCHUNK - 1) ci = NCHUNK - 1;  // lo == NNODE
  size_t hb = (size_t)hh * (NNODE + 1);
  size_t co = ((size_t)hh * NCHUNK + ci) * TW;
  float wp = expf(tv), wm = expf(NEG * tv);
  float num = wp * (SS[(hb + lo) * TW + c] + fP[co + c]) +
              wm * (PP[(hb + lo) * TW + c] + fM[co + c]);
  float Z = wp * (SS[(hb + lo) * TW + 128] + fP[co + 128]) +
            wm * (PP[(hb + lo) * TW + 128] + fM[co + 128]);
  float ov = num / Z + bias[hh * CDIM + c];
  float r = (ov > 0.f) ? ov : (expf(ov) - 1.f);
  if constexpr (MEANOUT) {
    atomicAdd(&mpart[(blockIdx.x & 63) * CDIM + c], r);
  } else if constexpr (sizeof(OUT) == 2) {
    out[(size_t)n * (H * CDIM) + hh * CDIM + c] = f2b(r);
  } else {
    out[(size_t)n * (H * CDIM) + hh * CDIM + c] = r;
  }
}

// Reduce the 64x128 partials (redundantly per block, trivial) then GEMV.
__global__ __launch_bounds__(256) void fc_kernel(const float* __restrict__ part,
                                                 const float* __restrict__ fcW,
                                                 const float* __restrict__ fcb,
                                                 float* __restrict__ out) {
  __shared__ float tmp[256];
  __shared__ float m[CDIM];
  int tid = threadIdx.x;
  int c = tid & 127, half = tid >> 7;
  float a = 0.f;
  for (int g = half; g < 64; g += 2) a += part[g * CDIM + c];
  tmp[tid] = a; __syncthreads();
  if (tid < 128) m[tid] = (tmp[tid] + tmp[tid + 128]) * (1.f / NNODE);
  __syncthreads();
  int d = blockIdx.x * 256 + tid;  // 768 total
  float acc = fcb[d];
#pragma unroll 4
  for (int c2 = 0; c2 < CDIM; c2++) acc = fmaf(m[c2], fcW[c2 * 768 + d], acc);
  out[d] = acc;
}

extern "C" void kernel_launch(void* const* d_in, const int* in_sizes, int n_in,
                              void* d_out, int out_size, void* d_ws, size_t ws_size,
                              hipStream_t stream) {
  const float* x   = (const float*)d_in[0];
  const float* W1  = (const float*)d_in[1];
  const float* as1 = (const float*)d_in[2];
  const float* ad1 = (const float*)d_in[3];
  const float* b1  = (const float*)d_in[4];
  const float* W2  = (const float*)d_in[5];
  const float* as2 = (const float*)d_in[6];
  const float* ad2 = (const float*)d_in[7];
  const float* b2  = (const float*)d_in[8];
  const float* fcW = (const float*)d_in[9];
  const float* fcb = (const float*)d_in[10];

  float* ws = (float*)d_ws;
  size_t off = 0;
  auto alloc = [&](size_t nfloats) { float* p = ws + off; off += nfloats; return p; };

  float* h1  = alloc((size_t)NNODE * 512);
  float* x2f = alloc((size_t)NNODE * 256 + 64 + 16384);  // x2b bf16 + W2t bf16
  float* h2  = alloc((size_t)NNODE * 128);
  float* s1  = alloc((size_t)4 * NNODE);
  float* t1  = alloc((size_t)4 * NNODE);
  float* sS1 = alloc((size_t)4 * NNODE);
  int*   sI1 = (int*)alloc((size_t)4 * NNODE);
  int*   qL1 = (int*)alloc((size_t)4 * NNODE);
  float* SS1 = alloc((size_t)4 * (NNODE + 1) * TW);
  float* PP1 = alloc((size_t)4 * (NNODE + 1) * TW);
  float* pP1 = alloc((size_t)4 * NCHUNK * TW);
  float* pM1 = alloc((size_t)4 * NCHUNK * TW);
  float* fP1 = alloc((size_t)4 * NCHUNK * TW);   // chunk suffix of P
  float* fM1 = alloc((size_t)4 * NCHUNK * TW);   // chunk prefix of M
  float* s2  = alloc(NNODE);
  float* t2  = alloc(NNODE);
  float* sS2 = alloc(NNODE);
  int*   sI2 = (int*)alloc(NNODE);
  int*   qL2 = (int*)alloc(NNODE);
  float* SS2 = alloc((size_t)(NNODE + 1) * TW);
  float* PP2 = alloc((size_t)(NNODE + 1) * TW);
  float* pP2 = alloc((size_t)NCHUNK * TW);
  float* pM2 = alloc((size_t)NCHUNK * TW);
  float* fP2 = alloc((size_t)NCHUNK * TW);
  float* fM2 = alloc((size_t)NCHUNK * TW);
  float* mpart = alloc((size_t)64 * CDIM);  // mean bins (attend2 atomics)

  // bf16 staging aliased into PP1/SS1 (first written by passAC1, strictly
  // after gemm1 last reads them — stream ordered).
  unsigned short* xb  = (unsigned short*)PP1;  // 4096x768 bf16 = 6.3 MB (< 8.65 MB)
  unsigned short* W1t = (unsigned short*)SS1;  // 512x768 bf16
  unsigned short* x2b = (unsigned short*)x2f;                       // 4096x512 bf16
  unsigned short* W2t = (unsigned short*)(x2f + NNODE * 256 + 64);  // 128x512 bf16

  // Prep: convert x + transpose/cast W1, W2 + zero s/t accumulators + mpart
  prep_kernel<<<3232, 256, 0, stream>>>(x, W1, W2, xb, W1t, W2t, s1, s2, mpart);
  // Layer 1 (fused s/t epilogue)
  mfma_gemm_bt<64, 64><<<dim3(512 / 64, NNODE / 64), 256, 0, stream>>>(
      xb, W1t, h1, NNODE, 512, 768, s1, t1, as1, ad1);
  rank_sort_kernel<<<dim3(NNODE / 32, 4), 256, 0, stream>>>(s1, t1, sS1, sI1, qL1);
  passAC_kernel<<<4 * NCHUNK, 128, 0, stream>>>(h1, sS1, sI1, pP1, pM1, SS1, PP1, 4);
  passB_kernel<<<dim3(2, 4), 192, 0, stream>>>(pP1, pM1, fP1, fM1);
  attend_kernel<unsigned short, false><<<NNODE * 4 / 2, 256, 0, stream>>>(
      SS1, PP1, fP1, fM1, qL1, t1, b1, x2b, nullptr, 4);
  // Layer 2 (fused s/t epilogue)
  mfma_gemm_bt<32, 64><<<dim3(128 / 64, NNODE / 32), 256, 0, stream>>>(
      x2b, W2t, h2, NNODE, 128, 512, s2, t2, as2, ad2);
  rank_sort_kernel<<<dim3(NNODE / 32, 1), 256, 0, stream>>>(s2, t2, sS2, sI2, qL2);
  passAC_kernel<<<NCHUNK, 128, 0, stream>>>(h2, sS2, sI2, pP2, pM2, SS2, PP2, 1);
  passB_kernel<<<dim3(2, 1), 192, 0, stream>>>(pP2, pM2, fP2, fM2);
  attend_kernel<float, true><<<NNODE / 2, 256, 0, stream>>>(
      SS2, PP2, fP2, fM2, qL2, t2, b2, (float*)nullptr, mpart, 1);
  // Readout: fc straight off the mean bins
  fc_kernel<<<3, 256, 0, stream>>>(mpart, fcW, fcb, (float*)d_out);
}

// Round 10
// 206.413 us; speedup vs baseline: 9.2403x; 1.1371x over previous
//
#include <hip/hip_runtime.h>
#include <hip/hip_bf16.h>

// FacePartGAT: dense-graph GATConv x2 + mean + fc on MI355X. ALL I/O fp32.
// e[i,j] = leaky_relu(t_i + s_j) => softmax aggregation factorizes after
// sorting sources by s_j (prefix/suffix tables + split-point lookup). Exact.
// Round 21: R20's BK=64 GEMM was an 8-way LDS write-bank-conflict regression
// (stride-72 rows: bank = 4*(r+c) mod 32; SQ_LDS_BANK_CONFLICT 786K,
// MfmaUtil 2.6%, gemm1 43us). Revert to R16's exact BK=32/stride-40 GEMM
// (2-way write aliasing = free). KEEP the attend2 mean fusion (atomicAdd
// into 64x128 bins; drops mean_part dispatch + x3 traffic).

#define NNODE 4096
#define CDIM 128
#define TW 132           // table width: 128 features + z at col 128
#define NEG 0.2f
#define CHUNK 32
#define NCHUNK 128       // NNODE / CHUNK

typedef __bf16 bf16x8 __attribute__((ext_vector_type(8)));
typedef float f32x4 __attribute__((ext_vector_type(4)));

__device__ __forceinline__ unsigned short f2b(float f) {
  unsigned int u = __float_as_uint(f);
  u += 0x7fffu + ((u >> 16) & 1u);  // RTNE
  return (unsigned short)(u >> 16);
}

// One kernel: [0,3072) convert x -> bf16; [3072,3168) W1 transpose;
// [3168,3184) W2 transpose; [3184,3216) zero s1/t1; [3216,3224) zero s2/t2;
// [3224,3232) zero mpart.
__global__ __launch_bounds__(256) void prep_kernel(const float* __restrict__ x,
                                                   const float* __restrict__ W1,
                                                   const float* __restrict__ W2,
                                                   unsigned short* __restrict__ xb,
                                                   unsigned short* __restrict__ W1t,
                                                   unsigned short* __restrict__ W2t,
                                                   float* __restrict__ zs1,
                                                   float* __restrict__ zs2,
                                                   float* __restrict__ zmp) {
  __shared__ float tile[64][65];
  int b = blockIdx.x, t = threadIdx.x;
  if (b < 3072) {  // convert x: 4096*768/4 quads
    int i = b * 256 + t;
    float4 v = ((const float4*)x)[i];
    ushort4 o;
    o.x = f2b(v.x); o.y = f2b(v.y); o.z = f2b(v.z); o.w = f2b(v.w);
    ((ushort4*)xb)[i] = o;
    return;
  }
  if (b >= 3184) {  // zero regions
    float4 z = {0.f, 0.f, 0.f, 0.f};
    if (b < 3216) {
      ((float4*)zs1)[(b - 3184) * 256 + t] = z;       // s1+t1: 32768 floats
    } else if (b < 3224) {
      ((float4*)zs2)[(b - 3216) * 256 + t] = z;       // s2+t2: 8192 floats
    } else {
      ((float4*)zmp)[(b - 3224) * 256 + t] = z;       // mpart: 8192 floats
    }
    return;
  }
  const float* W; unsigned short* Wt; int K, N, n0, k0;
  if (b < 3072 + 96) {  // W1 [768,512] -> W1t [512,768]
    int b2 = b - 3072; W = W1; Wt = W1t; K = 768; N = 512;
    n0 = (b2 & 7) * 64; k0 = (b2 >> 3) * 64;
  } else {              // W2 [512,128] -> W2t [128,512]
    int b3 = b - 3072 - 96; W = W2; Wt = W2t; K = 512; N = 128;
    n0 = (b3 & 1) * 64; k0 = (b3 >> 1) * 64;
  }
  for (int p = 0; p < 16; p++) {
    int e = p * 256 + t;
    int rr = e >> 6, cc = e & 63;
    tile[rr][cc] = W[(size_t)(k0 + rr) * N + n0 + cc];
  }
  __syncthreads();
  for (int p = 0; p < 16; p++) {
    int e = p * 256 + t;
    int rr = e >> 6, cc = e & 63;  // rr: n-dir, cc: k-dir
    Wt[(size_t)(n0 + rr) * K + k0 + cc] = f2b(tile[cc][rr]);
  }
}

// C[M,N] = A[M,K] x Bt[N,K]^T, both bf16 K-contig. BK=32, 256 thr = 4 waves
// (2x2), stride-40 LDS rows (80 B: 2-way write aliasing = free). Register
// prefetch of tile k+1 between LDS barrier and MFMA.
// Fused epilogue: s/t row-dots from acc registers (shfl reduce + atomicAdd).
template <int BM, int BN>
__global__ __launch_bounds__(256) void mfma_gemm_bt(const unsigned short* __restrict__ A,
                                                    const unsigned short* __restrict__ Bt,
                                                    float* __restrict__ C,
                                                    int M, int N, int K,
                                                    float* __restrict__ sAcc,
                                                    float* __restrict__ tAcc,
                                                    const float* __restrict__ av_s,
                                                    const float* __restrict__ av_d) {
  __shared__ __align__(16) unsigned short As[BM * 40];
  __shared__ __align__(16) unsigned short Bs[BN * 40];
  constexpr int WM = BM / 2, WN = BN / 2;
  constexpr int FI = WM / 16, FJ = WN / 16;
  constexpr int EA = BM * 32 / 8;
  constexpr int EB = BN * 32 / 8;
  constexpr int NA = (EA + 255) / 256;
  constexpr int NB = (EB + 255) / 256;
  int tid = threadIdx.x;
  int lane = tid & 63, wave = tid >> 6;
  int wm = (wave >> 1) * WM, wn = (wave & 1) * WN;
  int m0 = blockIdx.y * BM, n0 = blockIdx.x * BN;
  int fm = lane & 15, fq = lane >> 4;
  f32x4 acc[FI][FJ] = {};
  uint4 ar[NA], br[NB];
  // preload tile 0
#pragma unroll
  for (int q = 0; q < NA; q++) {
    int e = q * 256 + tid;
    if (e < EA) {
      int r = e >> 2, kk = (e & 3) * 8;
      ar[q] = *(const uint4*)(A + (size_t)(m0 + r) * K + kk);
    }
  }
#pragma unroll
  for (int q = 0; q < NB; q++) {
    int e = q * 256 + tid;
    if (e < EB) {
      int r = e >> 2, kk = (e & 3) * 8;
      br[q] = *(const uint4*)(Bt + (size_t)(n0 + r) * K + kk);
    }
  }
  for (int k0 = 0; k0 < K; k0 += 32) {
    __syncthreads();  // previous iter's ds_reads done before overwrite
#pragma unroll
    for (int q = 0; q < NA; q++) {
      int e = q * 256 + tid;
      if (e < EA) {
        int r = e >> 2, kk = (e & 3) * 8;
        *(uint4*)&As[r * 40 + kk] = ar[q];
      }
    }
#pragma unroll
    for (int q = 0; q < NB; q++) {
      int e = q * 256 + tid;
      if (e < EB) {
        int r = e >> 2, kk = (e & 3) * 8;
        *(uint4*)&Bs[r * 40 + kk] = br[q];
      }
    }
    __syncthreads();
    // prefetch tile k+1 (in flight during ds_read + MFMA below)
    if (k0 + 32 < K) {
#pragma unroll
      for (int q = 0; q < NA; q++) {
        int e = q * 256 + tid;
        if (e < EA) {
          int r = e >> 2, kk = (e & 3) * 8;
          ar[q] = *(const uint4*)(A + (size_t)(m0 + r) * K + k0 + 32 + kk);
        }
      }
#pragma unroll
      for (int q = 0; q < NB; q++) {
        int e = q * 256 + tid;
        if (e < EB) {
          int r = e >> 2, kk = (e & 3) * 8;
          br[q] = *(const uint4*)(Bt + (size_t)(n0 + r) * K + k0 + 32 + kk);
        }
      }
    }
    bf16x8 af[FI], bfr[FJ];
#pragma unroll
    for (int i = 0; i < FI; i++)
      af[i] = *(const bf16x8*)&As[(wm + i * 16 + fm) * 40 + fq * 8];
#pragma unroll
    for (int j = 0; j < FJ; j++)
      bfr[j] = *(const bf16x8*)&Bs[(wn + j * 16 + fm) * 40 + fq * 8];
#pragma unroll
    for (int i = 0; i < FI; i++)
#pragma unroll
      for (int j = 0; j < FJ; j++)
        acc[i][j] = __builtin_amdgcn_mfma_f32_16x16x32_bf16(af[i], bfr[j], acc[i][j], 0, 0, 0);
  }
  // C store
#pragma unroll
  for (int i = 0; i < FI; i++) {
#pragma unroll
    for (int j = 0; j < FJ; j++) {
      int r = m0 + wm + i * 16 + fq * 4;
      int ccol = n0 + wn + j * 16 + fm;
#pragma unroll
      for (int reg = 0; reg < 4; reg++)
        C[(size_t)(r + reg) * N + ccol] = acc[i][j][reg];
    }
  }
  // fused s/t epilogue
  {
    int hh = n0 >> 7;
    float avs[FJ], avd[FJ];
#pragma unroll
    for (int j = 0; j < FJ; j++) {
      int col = n0 + wn + j * 16 + fm;
      avs[j] = av_s[col];
      avd[j] = av_d[col];
    }
#pragma unroll
    for (int i = 0; i < FI; i++) {
#pragma unroll
      for (int reg = 0; reg < 4; reg++) {
        float sv = 0.f, tv = 0.f;
#pragma unroll
        for (int j = 0; j < FJ; j++) {
          sv = fmaf(acc[i][j][reg], avs[j], sv);
          tv = fmaf(acc[i][j][reg], avd[j], tv);
        }
#pragma unroll
        for (int o = 1; o < 16; o <<= 1) {
          sv += __shfl_xor(sv, o, 64);
          tv += __shfl_xor(tv, o, 64);
        }
        if (fm == 0) {
          int row = m0 + wm + i * 16 + fq * 4 + reg;
          atomicAdd(&sAcc[(size_t)hh * NNODE + row], sv);
          atomicAdd(&tAcc[(size_t)hh * NNODE + row], tv);
        }
      }
    }
  }
}

// One-kernel rank sort + query split precompute. All 4096 keys in LDS
// (16 KB). Block = 32 nodes x 8 scan-parts of 512 keys; partial counts
// combined in LDS; direct scatter of (key, idx) to sorted position.
// ALSO counts lo[n] = #{j : s_j < -t_n} (strict <, == lower_bound).
__global__ __launch_bounds__(256) void rank_sort_kernel(const float* __restrict__ s,
                                                        const float* __restrict__ t,
                                                        float* __restrict__ ss,
                                                        int* __restrict__ si,
                                                        int* __restrict__ qlo) {
  __shared__ __align__(16) float keys[NNODE];
  __shared__ int pc[8][32], qc[8][32];
  int hh = blockIdx.y, tid = threadIdx.x;
  const float* sp = s + (size_t)hh * NNODE;
  for (int k = tid; k < NNODE / 4; k += 256)
    ((float4*)keys)[k] = ((const float4*)sp)[k];
  __syncthreads();
  int slot = tid & 31, part = tid >> 5;
  int node = blockIdx.x * 32 + slot;
  float mk = keys[node];
  float qk = -t[(size_t)hh * NNODE + node];
  int cnt = 0, cq = 0;
  int j0 = part * 512;
#pragma unroll 4
  for (int j = j0; j < j0 + 512; j += 4) {
    float4 kv = *(const float4*)&keys[j];
    cnt += (kv.x < mk) || (kv.x == mk && (j + 0) < node);
    cnt += (kv.y < mk) || (kv.y == mk && (j + 1) < node);
    cnt += (kv.z < mk) || (kv.z == mk && (j + 2) < node);
    cnt += (kv.w < mk) || (kv.w == mk && (j + 3) < node);
    cq += (kv.x < qk) + (kv.y < qk) + (kv.z < qk) + (kv.w < qk);
  }
  pc[part][slot] = cnt;
  qc[part][slot] = cq;
  __syncthreads();
  if (tid < 32) {
    int rank = 0;
#pragma unroll
    for (int p = 0; p < 8; p++) rank += pc[p][tid];
    int n2 = blockIdx.x * 32 + tid;
    ss[(size_t)hh * NNODE + rank] = keys[n2];
    si[(size_t)hh * NNODE + rank] = n2;
  } else if (tid < 64) {
    int sl = tid - 32;
    int lo = 0;
#pragma unroll
    for (int p = 0; p < 8; p++) lo += qc[p][sl];
    qlo[(size_t)hh * NNODE + blockIdx.x * 32 + sl] = lo;
  }
}

// Fused passA+passC: gather h rows ONCE, dual LOCAL scans (tables start at
// zero carry; attend adds chunk carries). The chunk partial sums for passB
// fall out as the scans' final running values. z at col 128.
__global__ __launch_bounds__(128) void passAC_kernel(const float* __restrict__ h,
                                                     const float* __restrict__ ss,
                                                     const int* __restrict__ si,
                                                     float* __restrict__ partP,
                                                     float* __restrict__ partM,
                                                     float* __restrict__ SS,
                                                     float* __restrict__ PP, int H) {
  __shared__ float hrow[CHUNK][CDIM];  // 16 KB
  __shared__ float eP[CHUNK], eM[CHUNK];
  __shared__ int ids[CHUNK];
  int b = blockIdx.x, hh = b / NCHUNK, ci = b % NCHUNK;
  int c = threadIdx.x;
  int HC = H * CDIM;
  int base = ci * CHUNK;
  size_t hb = (size_t)hh * (NNODE + 1);
  if (c < CHUNK) {
    float sv = ss[(size_t)hh * NNODE + base + c];
    ids[c] = si[(size_t)hh * NNODE + base + c];
    eP[c] = expf(sv);
    eM[c] = expf(NEG * sv);
  }
  __syncthreads();
  // gather h rows once into LDS (batched, per-thread column)
  for (int kb = 0; kb < CHUNK; kb += 8) {
    float v[8];
#pragma unroll
    for (int j = 0; j < 8; j++)
      v[j] = h[(size_t)ids[kb + j] * HC + hh * CDIM + c];
#pragma unroll
    for (int j = 0; j < 8; j++) hrow[kb + j][c] = v[j];
  }
  // M forward local prefix (exclusive); final run == chunk partial for passB
  float runm = 0.f, runzm = 0.f;
#pragma unroll 8
  for (int k = 0; k < CHUNK; k++) {
    size_t row = (hb + base + k) * TW;
    PP[row + c] = runm;
    if (c == 0) PP[row + 128] = runzm;
    runm = fmaf(eM[k], hrow[k][c], runm);
    runzm += eM[k];
  }
  size_t o = ((size_t)hh * NCHUNK + ci) * TW;
  partM[o + c] = runm;
  if (c == 0) partM[o + 128] = runzm;
  if (ci == NCHUNK - 1) {
    size_t row = (hb + NNODE) * TW;
    PP[row + c] = runm;
    if (c == 0) PP[row + 128] = runzm;
  }
  // P backward local suffix (inclusive); final run == chunk partial
  float runp = 0.f, runzp = 0.f;
#pragma unroll 8
  for (int k = CHUNK - 1; k >= 0; k--) {
    runp = fmaf(eP[k], hrow[k][c], runp);
    runzp += eP[k];
    size_t row = (hb + base + k) * TW;
    SS[row + c] = runp;
    if (c == 0) SS[row + 128] = runzp;
  }
  partP[o + c] = runp;
  if (c == 0) partP[o + 128] = runzp;
  if (ci == NCHUNK - 1) {
    size_t row = (hb + NNODE) * TW;
    SS[row + c] = 0.f;
    if (c == 0) SS[row + 128] = 0.f;
  }
}

// Pass B: per-head exclusive prefix scan of partM (forward) and exclusive
// suffix scan of partP (backward) over the NCHUNK chunk partials, incl. z.
__global__ __launch_bounds__(192) void passB_kernel(const float* __restrict__ partP,
                                                    const float* __restrict__ partM,
                                                    float* __restrict__ sufP,
                                                    float* __restrict__ prefM) {
  int hh = blockIdx.y, dir = blockIdx.x;
  int c = threadIdx.x;
  if (c > 128) return;  // 129 cols: 128 features + z
  size_t base = (size_t)hh * NCHUNK * TW;
  if (dir == 0) {  // forward exclusive prefix of partM
    float run = 0.f;
    for (int g0 = 0; g0 < NCHUNK; g0 += 8) {
      float v[8];
#pragma unroll
      for (int j = 0; j < 8; j++) v[j] = partM[base + (size_t)(g0 + j) * TW + c];
#pragma unroll
      for (int j = 0; j < 8; j++) {
        prefM[base + (size_t)(g0 + j) * TW + c] = run;
        run += v[j];
      }
    }
  } else {  // backward exclusive suffix of partP
    float run = 0.f;
    for (int g0 = NCHUNK - 8; g0 >= 0; g0 -= 8) {
      float v[8];
#pragma unroll
      for (int j = 7; j >= 0; j--) v[j] = partP[base + (size_t)(g0 + j) * TW + c];
#pragma unroll
      for (int j = 7; j >= 0; j--) {
        sufP[base + (size_t)(g0 + j) * TW + c] = run;
        run += v[j];
      }
    }
  }
}

// Per (dest, head): local table row at precomputed split + chunk carry
// (fP/fM, L2-resident), +bias, ELU. 2 queries per 256-thread block.
// MEANOUT: instead of storing rows, atomicAdd into 64x128 mean bins
// (bin = blockIdx & 63; 32 blocks/bin -> negligible contention).
template <typename OUT, bool MEANOUT>
__global__ __launch_bounds__(256) void attend_kernel(const float* __restrict__ SS,
                                                     const float* __restrict__ PP,
                                                     const float* __restrict__ fP,
                                                     const float* __restrict__ fM,
                                                     const int* __restrict__ qlo,
                                                     const float* __restrict__ tt,
                                                     const float* __restrict__ bias,
                                                     OUT* __restrict__ out,
                                                     float* __restrict__ mpart, int H) {
  int half = threadIdx.x >> 7, c = threadIdx.x & 127;
  int o = blockIdx.x * 2 + half;
  int n = o / H, hh = o % H;
  float tv = tt[(size_t)hh * NNODE + n];
  int lo = qlo[(size_t)hh * NNODE + n];
  int ci = lo >> 5;                      // CHUNK = 32
  if (ci > NCHUNK - 1) ci = NCHUNK - 1;  // lo == NNODE
  size_t hb = (size_t)hh * (NNODE + 1);
  size_t co = ((size_t)hh * NCHUNK + ci) * TW;
  float wp = expf(tv), wm = expf(NEG * tv);
  float num = wp * (SS[(hb + lo) * TW + c] + fP[co + c]) +
              wm * (PP[(hb + lo) * TW + c] + fM[co + c]);
  float Z = wp * (SS[(hb + lo) * TW + 128] + fP[co + 128]) +
            wm * (PP[(hb + lo) * TW + 128] + fM[co + 128]);
  float ov = num / Z + bias[hh * CDIM + c];
  float r = (ov > 0.f) ? ov : (expf(ov) - 1.f);
  if constexpr (MEANOUT) {
    atomicAdd(&mpart[(blockIdx.x & 63) * CDIM + c], r);
  } else if constexpr (sizeof(OUT) == 2) {
    out[(size_t)n * (H * CDIM) + hh * CDIM + c] = f2b(r);
  } else {
    out[(size_t)n * (H * CDIM) + hh * CDIM + c] = r;
  }
}

// Reduce the 64x128 partials (redundantly per block, trivial) then GEMV.
__global__ __launch_bounds__(256) void fc_kernel(const float* __restrict__ part,
                                                 const float* __restrict__ fcW,
                                                 const float* __restrict__ fcb,
                                                 float* __restrict__ out) {
  __shared__ float tmp[256];
  __shared__ float m[CDIM];
  int tid = threadIdx.x;
  int c = tid & 127, half = tid >> 7;
  float a = 0.f;
  for (int g = half; g < 64; g += 2) a += part[g * CDIM + c];
  tmp[tid] = a; __syncthreads();
  if (tid < 128) m[tid] = (tmp[tid] + tmp[tid + 128]) * (1.f / NNODE);
  __syncthreads();
  int d = blockIdx.x * 256 + tid;  // 768 total
  float acc = fcb[d];
#pragma unroll 4
  for (int c2 = 0; c2 < CDIM; c2++) acc = fmaf(m[c2], fcW[c2 * 768 + d], acc);
  out[d] = acc;
}

extern "C" void kernel_launch(void* const* d_in, const int* in_sizes, int n_in,
                              void* d_out, int out_size, void* d_ws, size_t ws_size,
                              hipStream_t stream) {
  const float* x   = (const float*)d_in[0];
  const float* W1  = (const float*)d_in[1];
  const float* as1 = (const float*)d_in[2];
  const float* ad1 = (const float*)d_in[3];
  const float* b1  = (const float*)d_in[4];
  const float* W2  = (const float*)d_in[5];
  const float* as2 = (const float*)d_in[6];
  const float* ad2 = (const float*)d_in[7];
  const float* b2  = (const float*)d_in[8];
  const float* fcW = (const float*)d_in[9];
  const float* fcb = (const float*)d_in[10];

  float* ws = (float*)d_ws;
  size_t off = 0;
  auto alloc = [&](size_t nfloats) { float* p = ws + off; off += nfloats; return p; };

  float* h1  = alloc((size_t)NNODE * 512);
  float* x2f = alloc((size_t)NNODE * 256 + 64 + 16384);  // x2b bf16 + W2t bf16
  float* h2  = alloc((size_t)NNODE * 128);
  float* s1  = alloc((size_t)4 * NNODE);
  float* t1  = alloc((size_t)4 * NNODE);
  float* sS1 = alloc((size_t)4 * NNODE);
  int*   sI1 = (int*)alloc((size_t)4 * NNODE);
  int*   qL1 = (int*)alloc((size_t)4 * NNODE);
  float* SS1 = alloc((size_t)4 * (NNODE + 1) * TW);
  float* PP1 = alloc((size_t)4 * (NNODE + 1) * TW);
  float* pP1 = alloc((size_t)4 * NCHUNK * TW);
  float* pM1 = alloc((size_t)4 * NCHUNK * TW);
  float* fP1 = alloc((size_t)4 * NCHUNK * TW);   // chunk suffix of P
  float* fM1 = alloc((size_t)4 * NCHUNK * TW);   // chunk prefix of M
  float* s2  = alloc(NNODE);
  float* t2  = alloc(NNODE);
  float* sS2 = alloc(NNODE);
  int*   sI2 = (int*)alloc(NNODE);
  int*   qL2 = (int*)alloc(NNODE);
  float* SS2 = alloc((size_t)(NNODE + 1) * TW);
  float* PP2 = alloc((size_t)(NNODE + 1) * TW);
  float* pP2 = alloc((size_t)NCHUNK * TW);
  float* pM2 = alloc((size_t)NCHUNK * TW);
  float* fP2 = alloc((size_t)NCHUNK * TW);
  float* fM2 = alloc((size_t)NCHUNK * TW);
  float* mpart = alloc((size_t)64 * CDIM);  // mean bins (attend2 atomics)

  // bf16 staging aliased into PP1/SS1 (first written by passAC1, strictly
  // after gemm1 last reads them — stream ordered).
  unsigned short* xb  = (unsigned short*)PP1;  // 4096x768 bf16 = 6.3 MB (< 8.65 MB)
  unsigned short* W1t = (unsigned short*)SS1;  // 512x768 bf16
  unsigned short* x2b = (unsigned short*)x2f;                       // 4096x512 bf16
  unsigned short* W2t = (unsigned short*)(x2f + NNODE * 256 + 64);  // 128x512 bf16

  // Prep: convert x + transpose/cast W1, W2 + zero s/t accumulators + mpart
  prep_kernel<<<3232, 256, 0, stream>>>(x, W1, W2, xb, W1t, W2t, s1, s2, mpart);
  // Layer 1 (fused s/t epilogue)
  mfma_gemm_bt<64, 64><<<dim3(512 / 64, NNODE / 64), 256, 0, stream>>>(
      xb, W1t, h1, NNODE, 512, 768, s1, t1, as1, ad1);
  rank_sort_kernel<<<dim3(NNODE / 32, 4), 256, 0, stream>>>(s1, t1, sS1, sI1, qL1);
  passAC_kernel<<<4 * NCHUNK, 128, 0, stream>>>(h1, sS1, sI1, pP1, pM1, SS1, PP1, 4);
  passB_kernel<<<dim3(2, 4), 192, 0, stream>>>(pP1, pM1, fP1, fM1);
  attend_kernel<unsigned short, false><<<NNODE * 4 / 2, 256, 0, stream>>>(
      SS1, PP1, fP1, fM1, qL1, t1, b1, x2b, nullptr, 4);
  // Layer 2 (fused s/t epilogue)
  mfma_gemm_bt<32, 64><<<dim3(128 / 64, NNODE / 32), 256, 0, stream>>>(
      x2b, W2t, h2, NNODE, 128, 512, s2, t2, as2, ad2);
  rank_sort_kernel<<<dim3(NNODE / 32, 1), 256, 0, stream>>>(s2, t2, sS2, sI2, qL2);
  passAC_kernel<<<NCHUNK, 128, 0, stream>>>(h2, sS2, sI2, pP2, pM2, SS2, PP2, 1);
  passB_kernel<<<dim3(2, 1), 192, 0, stream>>>(pP2, pM2, fP2, fM2);
  attend_kernel<float, true><<<NNODE / 2, 256, 0, stream>>>(
      SS2, PP2, fP2, fM2, qL2, t2, b2, (float*)nullptr, mpart, 1);
  // Readout: fc straight off the mean bins
  fc_kernel<<<3, 256, 0, stream>>>(mpart, fcW, fcb, (float*)d_out);
}

// Round 11
// 203.002 us; speedup vs baseline: 9.3956x; 1.0168x over previous
//
#include <hip/hip_runtime.h>
#include <hip/hip_bf16.h>

// FacePartGAT: dense-graph GATConv x2 + mean + fc on MI355X. ALL I/O fp32.
// e[i,j] = leaky_relu(t_i + s_j) => softmax aggregation factorizes after
// sorting sources by s_j (prefix/suffix tables + split-point lookup). Exact.
// Round 22: two counter-grounded micro-opts on the R21 structure:
//  - XCD-aware GEMM block swizzle (R9 counters: FETCH 30.7 MB vs ~7 MB
//    unique; dim3(8,64) puts the 8 blocks sharing an A-row-panel on 8
//    DIFFERENT XCD L2s). 1D grid, m0 = bid % mblocks -> all n-blocks of a
//    panel on one XCD; per-XCD working set ~1.5 MB (L2-resident).
//  - attend: 4 queries/block (ILP on the lo->table-row chain, half the
//    blocks).

#define NNODE 4096
#define CDIM 128
#define TW 132           // table width: 128 features + z at col 128
#define NEG 0.2f
#define CHUNK 32
#define NCHUNK 128       // NNODE / CHUNK

typedef __bf16 bf16x8 __attribute__((ext_vector_type(8)));
typedef float f32x4 __attribute__((ext_vector_type(4)));

__device__ __forceinline__ unsigned short f2b(float f) {
  unsigned int u = __float_as_uint(f);
  u += 0x7fffu + ((u >> 16) & 1u);  // RTNE
  return (unsigned short)(u >> 16);
}

// One kernel: [0,3072) convert x -> bf16; [3072,3168) W1 transpose;
// [3168,3184) W2 transpose; [3184,3216) zero s1/t1; [3216,3224) zero s2/t2;
// [3224,3232) zero mpart.
__global__ __launch_bounds__(256) void prep_kernel(const float* __restrict__ x,
                                                   const float* __restrict__ W1,
                                                   const float* __restrict__ W2,
                                                   unsigned short* __restrict__ xb,
                                                   unsigned short* __restrict__ W1t,
                                                   unsigned short* __restrict__ W2t,
                                                   float* __restrict__ zs1,
                                                   float* __restrict__ zs2,
                                                   float* __restrict__ zmp) {
  __shared__ float tile[64][65];
  int b = blockIdx.x, t = threadIdx.x;
  if (b < 3072) {  // convert x: 4096*768/4 quads
    int i = b * 256 + t;
    float4 v = ((const float4*)x)[i];
    ushort4 o;
    o.x = f2b(v.x); o.y = f2b(v.y); o.z = f2b(v.z); o.w = f2b(v.w);
    ((ushort4*)xb)[i] = o;
    return;
  }
  if (b >= 3184) {  // zero regions
    float4 z = {0.f, 0.f, 0.f, 0.f};
    if (b < 3216) {
      ((float4*)zs1)[(b - 3184) * 256 + t] = z;       // s1+t1: 32768 floats
    } else if (b < 3224) {
      ((float4*)zs2)[(b - 3216) * 256 + t] = z;       // s2+t2: 8192 floats
    } else {
      ((float4*)zmp)[(b - 3224) * 256 + t] = z;       // mpart: 8192 floats
    }
    return;
  }
  const float* W; unsigned short* Wt; int K, N, n0, k0;
  if (b < 3072 + 96) {  // W1 [768,512] -> W1t [512,768]
    int b2 = b - 3072; W = W1; Wt = W1t; K = 768; N = 512;
    n0 = (b2 & 7) * 64; k0 = (b2 >> 3) * 64;
  } else {              // W2 [512,128] -> W2t [128,512]
    int b3 = b - 3072 - 96; W = W2; Wt = W2t; K = 512; N = 128;
    n0 = (b3 & 1) * 64; k0 = (b3 >> 1) * 64;
  }
  for (int p = 0; p < 16; p++) {
    int e = p * 256 + t;
    int rr = e >> 6, cc = e & 63;
    tile[rr][cc] = W[(size_t)(k0 + rr) * N + n0 + cc];
  }
  __syncthreads();
  for (int p = 0; p < 16; p++) {
    int e = p * 256 + t;
    int rr = e >> 6, cc = e & 63;  // rr: n-dir, cc: k-dir
    Wt[(size_t)(n0 + rr) * K + k0 + cc] = f2b(tile[cc][rr]);
  }
}

// C[M,N] = A[M,K] x Bt[N,K]^T, both bf16 K-contig. BK=32, 256 thr = 4 waves
// (2x2), stride-40 LDS rows (80 B: 2-way write aliasing = free). Register
// prefetch of tile k+1 between LDS barrier and MFMA.
// 1D grid, XCD-swizzled: m0 = bid % mblocks -> all n-blocks sharing an
// A-row-panel have id === m0 (mod 8) -> same XCD L2 -> panel fetched once.
// Fused epilogue: s/t row-dots from acc registers (shfl reduce + atomicAdd).
template <int BM, int BN>
__global__ __launch_bounds__(256) void mfma_gemm_bt(const unsigned short* __restrict__ A,
                                                    const unsigned short* __restrict__ Bt,
                                                    float* __restrict__ C,
                                                    int M, int N, int K, int mblocks,
                                                    float* __restrict__ sAcc,
                                                    float* __restrict__ tAcc,
                                                    const float* __restrict__ av_s,
                                                    const float* __restrict__ av_d) {
  __shared__ __align__(16) unsigned short As[BM * 40];
  __shared__ __align__(16) unsigned short Bs[BN * 40];
  constexpr int WM = BM / 2, WN = BN / 2;
  constexpr int FI = WM / 16, FJ = WN / 16;
  constexpr int EA = BM * 32 / 8;
  constexpr int EB = BN * 32 / 8;
  constexpr int NA = (EA + 255) / 256;
  constexpr int NB = (EB + 255) / 256;
  int tid = threadIdx.x;
  int lane = tid & 63, wave = tid >> 6;
  int wm = (wave >> 1) * WM, wn = (wave & 1) * WN;
  int bid = blockIdx.x;
  int m0 = (bid % mblocks) * BM, n0 = (bid / mblocks) * BN;
  int fm = lane & 15, fq = lane >> 4;
  f32x4 acc[FI][FJ] = {};
  uint4 ar[NA], br[NB];
  // preload tile 0
#pragma unroll
  for (int q = 0; q < NA; q++) {
    int e = q * 256 + tid;
    if (e < EA) {
      int r = e >> 2, kk = (e & 3) * 8;
      ar[q] = *(const uint4*)(A + (size_t)(m0 + r) * K + kk);
    }
  }
#pragma unroll
  for (int q = 0; q < NB; q++) {
    int e = q * 256 + tid;
    if (e < EB) {
      int r = e >> 2, kk = (e & 3) * 8;
      br[q] = *(const uint4*)(Bt + (size_t)(n0 + r) * K + kk);
    }
  }
  for (int k0 = 0; k0 < K; k0 += 32) {
    __syncthreads();  // previous iter's ds_reads done before overwrite
#pragma unroll
    for (int q = 0; q < NA; q++) {
      int e = q * 256 + tid;
      if (e < EA) {
        int r = e >> 2, kk = (e & 3) * 8;
        *(uint4*)&As[r * 40 + kk] = ar[q];
      }
    }
#pragma unroll
    for (int q = 0; q < NB; q++) {
      int e = q * 256 + tid;
      if (e < EB) {
        int r = e >> 2, kk = (e & 3) * 8;
        *(uint4*)&Bs[r * 40 + kk] = br[q];
      }
    }
    __syncthreads();
    // prefetch tile k+1 (in flight during ds_read + MFMA below)
    if (k0 + 32 < K) {
#pragma unroll
      for (int q = 0; q < NA; q++) {
        int e = q * 256 + tid;
        if (e < EA) {
          int r = e >> 2, kk = (e & 3) * 8;
          ar[q] = *(const uint4*)(A + (size_t)(m0 + r) * K + k0 + 32 + kk);
        }
      }
#pragma unroll
      for (int q = 0; q < NB; q++) {
        int e = q * 256 + tid;
        if (e < EB) {
          int r = e >> 2, kk = (e & 3) * 8;
          br[q] = *(const uint4*)(Bt + (size_t)(n0 + r) * K + k0 + 32 + kk);
        }
      }
    }
    bf16x8 af[FI], bfr[FJ];
#pragma unroll
    for (int i = 0; i < FI; i++)
      af[i] = *(const bf16x8*)&As[(wm + i * 16 + fm) * 40 + fq * 8];
#pragma unroll
    for (int j = 0; j < FJ; j++)
      bfr[j] = *(const bf16x8*)&Bs[(wn + j * 16 + fm) * 40 + fq * 8];
#pragma unroll
    for (int i = 0; i < FI; i++)
#pragma unroll
      for (int j = 0; j < FJ; j++)
        acc[i][j] = __builtin_amdgcn_mfma_f32_16x16x32_bf16(af[i], bfr[j], acc[i][j], 0, 0, 0);
  }
  // C store
#pragma unroll
  for (int i = 0; i < FI; i++) {
#pragma unroll
    for (int j = 0; j < FJ; j++) {
      int r = m0 + wm + i * 16 + fq * 4;
      int ccol = n0 + wn + j * 16 + fm;
#pragma unroll
      for (int reg = 0; reg < 4; reg++)
        C[(size_t)(r + reg) * N + ccol] = acc[i][j][reg];
    }
  }
  // fused s/t epilogue
  {
    int hh = n0 >> 7;
    float avs[FJ], avd[FJ];
#pragma unroll
    for (int j = 0; j < FJ; j++) {
      int col = n0 + wn + j * 16 + fm;
      avs[j] = av_s[col];
      avd[j] = av_d[col];
    }
#pragma unroll
    for (int i = 0; i < FI; i++) {
#pragma unroll
      for (int reg = 0; reg < 4; reg++) {
        float sv = 0.f, tv = 0.f;
#pragma unroll
        for (int j = 0; j < FJ; j++) {
          sv = fmaf(acc[i][j][reg], avs[j], sv);
          tv = fmaf(acc[i][j][reg], avd[j], tv);
        }
#pragma unroll
        for (int o = 1; o < 16; o <<= 1) {
          sv += __shfl_xor(sv, o, 64);
          tv += __shfl_xor(tv, o, 64);
        }
        if (fm == 0) {
          int row = m0 + wm + i * 16 + fq * 4 + reg;
          atomicAdd(&sAcc[(size_t)hh * NNODE + row], sv);
          atomicAdd(&tAcc[(size_t)hh * NNODE + row], tv);
        }
      }
    }
  }
}

// One-kernel rank sort + query split precompute. All 4096 keys in LDS
// (16 KB). Block = 32 nodes x 8 scan-parts of 512 keys; partial counts
// combined in LDS; direct scatter of (key, idx) to sorted position.
// ALSO counts lo[n] = #{j : s_j < -t_n} (strict <, == lower_bound).
__global__ __launch_bounds__(256) void rank_sort_kernel(const float* __restrict__ s,
                                                        const float* __restrict__ t,
                                                        float* __restrict__ ss,
                                                        int* __restrict__ si,
                                                        int* __restrict__ qlo) {
  __shared__ __align__(16) float keys[NNODE];
  __shared__ int pc[8][32], qc[8][32];
  int hh = blockIdx.y, tid = threadIdx.x;
  const float* sp = s + (size_t)hh * NNODE;
  for (int k = tid; k < NNODE / 4; k += 256)
    ((float4*)keys)[k] = ((const float4*)sp)[k];
  __syncthreads();
  int slot = tid & 31, part = tid >> 5;
  int node = blockIdx.x * 32 + slot;
  float mk = keys[node];
  float qk = -t[(size_t)hh * NNODE + node];
  int cnt = 0, cq = 0;
  int j0 = part * 512;
#pragma unroll 4
  for (int j = j0; j < j0 + 512; j += 4) {
    float4 kv = *(const float4*)&keys[j];
    cnt += (kv.x < mk) || (kv.x == mk && (j + 0) < node);
    cnt += (kv.y < mk) || (kv.y == mk && (j + 1) < node);
    cnt += (kv.z < mk) || (kv.z == mk && (j + 2) < node);
    cnt += (kv.w < mk) || (kv.w == mk && (j + 3) < node);
    cq += (kv.x < qk) + (kv.y < qk) + (kv.z < qk) + (kv.w < qk);
  }
  pc[part][slot] = cnt;
  qc[part][slot] = cq;
  __syncthreads();
  if (tid < 32) {
    int rank = 0;
#pragma unroll
    for (int p = 0; p < 8; p++) rank += pc[p][tid];
    int n2 = blockIdx.x * 32 + tid;
    ss[(size_t)hh * NNODE + rank] = keys[n2];
    si[(size_t)hh * NNODE + rank] = n2;
  } else if (tid < 64) {
    int sl = tid - 32;
    int lo = 0;
#pragma unroll
    for (int p = 0; p < 8; p++) lo += qc[p][sl];
    qlo[(size_t)hh * NNODE + blockIdx.x * 32 + sl] = lo;
  }
}

// Fused passA+passC: gather h rows ONCE, dual LOCAL scans (tables start at
// zero carry; attend adds chunk carries). The chunk partial sums for passB
// fall out as the scans' final running values. z at col 128.
__global__ __launch_bounds__(128) void passAC_kernel(const float* __restrict__ h,
                                                     const float* __restrict__ ss,
                                                     const int* __restrict__ si,
                                                     float* __restrict__ partP,
                                                     float* __restrict__ partM,
                                                     float* __restrict__ SS,
                                                     float* __restrict__ PP, int H) {
  __shared__ float hrow[CHUNK][CDIM];  // 16 KB
  __shared__ float eP[CHUNK], eM[CHUNK];
  __shared__ int ids[CHUNK];
  int b = blockIdx.x, hh = b / NCHUNK, ci = b % NCHUNK;
  int c = threadIdx.x;
  int HC = H * CDIM;
  int base = ci * CHUNK;
  size_t hb = (size_t)hh * (NNODE + 1);
  if (c < CHUNK) {
    float sv = ss[(size_t)hh * NNODE + base + c];
    ids[c] = si[(size_t)hh * NNODE + base + c];
    eP[c] = expf(sv);
    eM[c] = expf(NEG * sv);
  }
  __syncthreads();
  // gather h rows once into LDS (batched, per-thread column)
  for (int kb = 0; kb < CHUNK; kb += 8) {
    float v[8];
#pragma unroll
    for (int j = 0; j < 8; j++)
      v[j] = h[(size_t)ids[kb + j] * HC + hh * CDIM + c];
#pragma unroll
    for (int j = 0; j < 8; j++) hrow[kb + j][c] = v[j];
  }
  // M forward local prefix (exclusive); final run == chunk partial for passB
  float runm = 0.f, runzm = 0.f;
#pragma unroll 8
  for (int k = 0; k < CHUNK; k++) {
    size_t row = (hb + base + k) * TW;
    PP[row + c] = runm;
    if (c == 0) PP[row + 128] = runzm;
    runm = fmaf(eM[k], hrow[k][c], runm);
    runzm += eM[k];
  }
  size_t o = ((size_t)hh * NCHUNK + ci) * TW;
  partM[o + c] = runm;
  if (c == 0) partM[o + 128] = runzm;
  if (ci == NCHUNK - 1) {
    size_t row = (hb + NNODE) * TW;
    PP[row + c] = runm;
    if (c == 0) PP[row + 128] = runzm;
  }
  // P backward local suffix (inclusive); final run == chunk partial
  float runp = 0.f, runzp = 0.f;
#pragma unroll 8
  for (int k = CHUNK - 1; k >= 0; k--) {
    runp = fmaf(eP[k], hrow[k][c], runp);
    runzp += eP[k];
    size_t row = (hb + base + k) * TW;
    SS[row + c] = runp;
    if (c == 0) SS[row + 128] = runzp;
  }
  partP[o + c] = runp;
  if (c == 0) partP[o + 128] = runzp;
  if (ci == NCHUNK - 1) {
    size_t row = (hb + NNODE) * TW;
    SS[row + c] = 0.f;
    if (c == 0) SS[row + 128] = 0.f;
  }
}

// Pass B: per-head exclusive prefix scan of partM (forward) and exclusive
// suffix scan of partP (backward) over the NCHUNK chunk partials, incl. z.
__global__ __launch_bounds__(192) void passB_kernel(const float* __restrict__ partP,
                                                    const float* __restrict__ partM,
                                                    float* __restrict__ sufP,
                                                    float* __restrict__ prefM) {
  int hh = blockIdx.y, dir = blockIdx.x;
  int c = threadIdx.x;
  if (c > 128) return;  // 129 cols: 128 features + z
  size_t base = (size_t)hh * NCHUNK * TW;
  if (dir == 0) {  // forward exclusive prefix of partM
    float run = 0.f;
    for (int g0 = 0; g0 < NCHUNK; g0 += 8) {
      float v[8];
#pragma unroll
      for (int j = 0; j < 8; j++) v[j] = partM[base + (size_t)(g0 + j) * TW + c];
#pragma unroll
      for (int j = 0; j < 8; j++) {
        prefM[base + (size_t)(g0 + j) * TW + c] = run;
        run += v[j];
      }
    }
  } else {  // backward exclusive suffix of partP
    float run = 0.f;
    for (int g0 = NCHUNK - 8; g0 >= 0; g0 -= 8) {
      float v[8];
#pragma unroll
      for (int j = 7; j >= 0; j--) v[j] = partP[base + (size_t)(g0 + j) * TW + c];
#pragma unroll
      for (int j = 7; j >= 0; j--) {
        sufP[base + (size_t)(g0 + j) * TW + c] = run;
        run += v[j];
      }
    }
  }
}

// Per (dest, head): local table row at precomputed split + chunk carry
// (fP/fM, L2-resident), +bias, ELU. 4 queries per 256-thread block (2 per
// half, sequential iterations -> independent loads overlap).
// MEANOUT: atomicAdd into 64x128 mean bins instead of storing rows.
template <typename OUT, bool MEANOUT>
__global__ __launch_bounds__(256) void attend_kernel(const float* __restrict__ SS,
                                                     const float* __restrict__ PP,
                                                     const float* __restrict__ fP,
                                                     const float* __restrict__ fM,
                                                     const int* __restrict__ qlo,
                                                     const float* __restrict__ tt,
                                                     const float* __restrict__ bias,
                                                     OUT* __restrict__ out,
                                                     float* __restrict__ mpart, int H) {
  int half = threadIdx.x >> 7, c = threadIdx.x & 127;
#pragma unroll
  for (int it = 0; it < 2; it++) {
    int o = blockIdx.x * 4 + it * 2 + half;
    int n = o / H, hh = o % H;
    float tv = tt[(size_t)hh * NNODE + n];
    int lo = qlo[(size_t)hh * NNODE + n];
    int ci = lo >> 5;                      // CHUNK = 32
    if (ci > NCHUNK - 1) ci = NCHUNK - 1;  // lo == NNODE
    size_t hb = (size_t)hh * (NNODE + 1);
    size_t co = ((size_t)hh * NCHUNK + ci) * TW;
    float wp = expf(tv), wm = expf(NEG * tv);
    float num = wp * (SS[(hb + lo) * TW + c] + fP[co + c]) +
                wm * (PP[(hb + lo) * TW + c] + fM[co + c]);
    float Z = wp * (SS[(hb + lo) * TW + 128] + fP[co + 128]) +
              wm * (PP[(hb + lo) * TW + 128] + fM[co + 128]);
    float ov = num / Z + bias[hh * CDIM + c];
    float r = (ov > 0.f) ? ov : (expf(ov) - 1.f);
    if constexpr (MEANOUT) {
      atomicAdd(&mpart[(blockIdx.x & 63) * CDIM + c], r);
    } else if constexpr (sizeof(OUT) == 2) {
      out[(size_t)n * (H * CDIM) + hh * CDIM + c] = f2b(r);
    } else {
      out[(size_t)n * (H * CDIM) + hh * CDIM + c] = r;
    }
  }
}

// Reduce the 64x128 partials (redundantly per block, trivial) then GEMV.
__global__ __launch_bounds__(256) void fc_kernel(const float* __restrict__ part,
                                                 const float* __restrict__ fcW,
                                                 const float* __restrict__ fcb,
                                                 float* __restrict__ out) {
  __shared__ float tmp[256];
  __shared__ float m[CDIM];
  int tid = threadIdx.x;
  int c = tid & 127, half = tid >> 7;
  float a = 0.f;
  for (int g = half; g < 64; g += 2) a += part[g * CDIM + c];
  tmp[tid] = a; __syncthreads();
  if (tid < 128) m[tid] = (tmp[tid] + tmp[tid + 128]) * (1.f / NNODE);
  __syncthreads();
  int d = blockIdx.x * 256 + tid;  // 768 total
  float acc = fcb[d];
#pragma unroll 4
  for (int c2 = 0; c2 < CDIM; c2++) acc = fmaf(m[c2], fcW[c2 * 768 + d], acc);
  out[d] = acc;
}

extern "C" void kernel_launch(void* const* d_in, const int* in_sizes, int n_in,
                              void* d_out, int out_size, void* d_ws, size_t ws_size,
                              hipStream_t stream) {
  const float* x   = (const float*)d_in[0];
  const float* W1  = (const float*)d_in[1];
  const float* as1 = (const float*)d_in[2];
  const float* ad1 = (const float*)d_in[3];
  const float* b1  = (const float*)d_in[4];
  const float* W2  = (const float*)d_in[5];
  const float* as2 = (const float*)d_in[6];
  const float* ad2 = (const float*)d_in[7];
  const float* b2  = (const float*)d_in[8];
  const float* fcW = (const float*)d_in[9];
  const float* fcb = (const float*)d_in[10];

  float* ws = (float*)d_ws;
  size_t off = 0;
  auto alloc = [&](size_t nfloats) { float* p = ws + off; off += nfloats; return p; };

  float* h1  = alloc((size_t)NNODE * 512);
  float* x2f = alloc((size_t)NNODE * 256 + 64 + 16384);  // x2b bf16 + W2t bf16
  float* h2  = alloc((size_t)NNODE * 128);
  float* s1  = alloc((size_t)4 * NNODE);
  float* t1  = alloc((size_t)4 * NNODE);
  float* sS1 = alloc((size_t)4 * NNODE);
  int*   sI1 = (int*)alloc((size_t)4 * NNODE);
  int*   qL1 = (int*)alloc((size_t)4 * NNODE);
  float* SS1 = alloc((size_t)4 * (NNODE + 1) * TW);
  float* PP1 = alloc((size_t)4 * (NNODE + 1) * TW);
  float* pP1 = alloc((size_t)4 * NCHUNK * TW);
  float* pM1 = alloc((size_t)4 * NCHUNK * TW);
  float* fP1 = alloc((size_t)4 * NCHUNK * TW);   // chunk suffix of P
  float* fM1 = alloc((size_t)4 * NCHUNK * TW);   // chunk prefix of M
  float* s2  = alloc(NNODE);
  float* t2  = alloc(NNODE);
  float* sS2 = alloc(NNODE);
  int*   sI2 = (int*)alloc(NNODE);
  int*   qL2 = (int*)alloc(NNODE);
  float* SS2 = alloc((size_t)(NNODE + 1) * TW);
  float* PP2 = alloc((size_t)(NNODE + 1) * TW);
  float* pP2 = alloc((size_t)NCHUNK * TW);
  float* pM2 = alloc((size_t)NCHUNK * TW);
  float* fP2 = alloc((size_t)NCHUNK * TW);
  float* fM2 = alloc((size_t)NCHUNK * TW);
  float* mpart = alloc((size_t)64 * CDIM);  // mean bins (attend2 atomics)

  // bf16 staging aliased into PP1/SS1 (first written by passAC1, strictly
  // after gemm1 last reads them — stream ordered).
  unsigned short* xb  = (unsigned short*)PP1;  // 4096x768 bf16 = 6.3 MB (< 8.65 MB)
  unsigned short* W1t = (unsigned short*)SS1;  // 512x768 bf16
  unsigned short* x2b = (unsigned short*)x2f;                       // 4096x512 bf16
  unsigned short* W2t = (unsigned short*)(x2f + NNODE * 256 + 64);  // 128x512 bf16

  // Prep: convert x + transpose/cast W1, W2 + zero s/t accumulators + mpart
  prep_kernel<<<3232, 256, 0, stream>>>(x, W1, W2, xb, W1t, W2t, s1, s2, mpart);
  // Layer 1 (fused s/t epilogue; XCD-swizzled 1D grid: 64 m-blocks x 8 n)
  mfma_gemm_bt<64, 64><<<512, 256, 0, stream>>>(
      xb, W1t, h1, NNODE, 512, 768, 64, s1, t1, as1, ad1);
  rank_sort_kernel<<<dim3(NNODE / 32, 4), 256, 0, stream>>>(s1, t1, sS1, sI1, qL1);
  passAC_kernel<<<4 * NCHUNK, 128, 0, stream>>>(h1, sS1, sI1, pP1, pM1, SS1, PP1, 4);
  passB_kernel<<<dim3(2, 4), 192, 0, stream>>>(pP1, pM1, fP1, fM1);
  attend_kernel<unsigned short, false><<<NNODE * 4 / 4, 256, 0, stream>>>(
      SS1, PP1, fP1, fM1, qL1, t1, b1, x2b, nullptr, 4);
  // Layer 2 (fused s/t epilogue; XCD-swizzled 1D grid: 128 m-blocks x 2 n)
  mfma_gemm_bt<32, 64><<<256, 256, 0, stream>>>(
      x2b, W2t, h2, NNODE, 128, 512, 128, s2, t2, as2, ad2);
  rank_sort_kernel<<<dim3(NNODE / 32, 1), 256, 0, stream>>>(s2, t2, sS2, sI2, qL2);
  passAC_kernel<<<NCHUNK, 128, 0, stream>>>(h2, sS2, sI2, pP2, pM2, SS2, PP2, 1);
  passB_kernel<<<dim3(2, 1), 192, 0, stream>>>(pP2, pM2, fP2, fM2);
  attend_kernel<float, true><<<NNODE / 4, 256, 0, stream>>>(
      SS2, PP2, fP2, fM2, qL2, t2, b2, (float*)nullptr, mpart, 1);
  // Readout: fc straight off the mean bins
  fc_kernel<<<3, 256, 0, stream>>>(mpart, fcW, fcb, (float*)d_out);
}